// Round 14
// baseline (217.137 us; speedup 1.0000x reference)
//
#include <hip/hip_runtime.h>
#include <hip/hip_bf16.h>
#include <stdint.h>

// Problem constants
#define TSEQ 2048
#define NB   4
#define NHEAD 16
#define HDIM 64
#define DM   1024
#define BTOT (NB*TSEQ)   // 8192 tokens

typedef __attribute__((ext_vector_type(8))) short bf16x8;   // 8 bf16 (4 VGPRs)
typedef __attribute__((ext_vector_type(4))) float f32x4;    // 16x16 MFMA C/D
typedef __attribute__((ext_vector_type(16))) float f32x16;  // 32x32 MFMA C/D
typedef __attribute__((ext_vector_type(2))) unsigned u32x2;

__device__ __forceinline__ unsigned short f2bf(float f){
  union { float f; unsigned u; } v; v.f = f;
  unsigned r = v.u + 0x7fffu + ((v.u >> 16) & 1u);   // RNE
  return (unsigned short)(r >> 16);
}

__device__ __forceinline__ unsigned cvt_pk_bf16(float lo, float hi){
  unsigned r;
  asm("v_cvt_pk_bf16_f32 %0, %1, %2" : "=v"(r) : "v"(lo), "v"(hi));
  return r;
}

// raw 2^x via compiler-aware intrinsic (R11-verified win vs exp2f libcall)
__device__ __forceinline__ float exp2_raw(float x){
#if __has_builtin(__builtin_amdgcn_exp2f)
  return __builtin_amdgcn_exp2f(x);
#else
  return exp2f(x);
#endif
}

__device__ __forceinline__ u32x2 pl32swap(unsigned a, unsigned b){
  auto r = __builtin_amdgcn_permlane32_swap((int)a, (int)b, false, false);
  return (u32x2){(unsigned)r[0], (unsigned)r[1]};
}

__device__ __forceinline__ void gload_lds16(const void* g, void* l){
  __builtin_amdgcn_global_load_lds(
      (const __attribute__((address_space(1))) void*)g,
      (__attribute__((address_space(3))) void*)l,
      16, 0, 0);
}

// ---------- fused prep: x cast (blocks 0..8191, FULL coverage) + 4 weight transposes ----------
__global__ __launch_bounds__(256) void k_prep(
    const float* __restrict__ x, unsigned short* __restrict__ x_bf,
    const float* __restrict__ Wq, const float* __restrict__ Wk,
    const float* __restrict__ Wv, const float* __restrict__ Wp,
    unsigned short* __restrict__ Wq_t, unsigned short* __restrict__ Wk_t,
    unsigned short* __restrict__ Wv_t, unsigned short* __restrict__ Wp_t)
{
  __shared__ unsigned short tile_s[32][33];
  const int bid = blockIdx.x;
  if (bid < 8192){
    size_t j = ((size_t)bid * 256 + threadIdx.x) * 4;
    float4 v = *reinterpret_cast<const float4*>(x + j);
    unsigned long long pk =  (unsigned long long)f2bf(v.x)
                          | ((unsigned long long)f2bf(v.y) << 16)
                          | ((unsigned long long)f2bf(v.z) << 32)
                          | ((unsigned long long)f2bf(v.w) << 48);
    *reinterpret_cast<unsigned long long*>(x_bf + j) = pk;
  } else {
    const int r   = bid - 8192;
    const int job = r >> 10, tile = r & 1023;
    const float* W = (job == 0) ? Wq : (job == 1) ? Wk : (job == 2) ? Wv : Wp;
    unsigned short* Wt = (job == 0) ? Wq_t : (job == 1) ? Wk_t : (job == 2) ? Wv_t : Wp_t;
    const int n0 = (tile & 31) * 32, k0 = (tile >> 5) * 32;
    const int tx = threadIdx.x & 31, ty = threadIdx.x >> 5;   // 32 x 8
    #pragma unroll
    for (int j = ty; j < 32; j += 8)
      tile_s[j][tx] = f2bf(W[(size_t)(k0 + j) * DM + n0 + tx]);
    __syncthreads();
    #pragma unroll
    for (int j = ty; j < 32; j += 8)
      Wt[(size_t)(n0 + j) * DM + k0 + tx] = tile_s[tx][j];
  }
}

// ---------- bf16 GEMM v3: templated tile, BK=64, 8 waves, 2-barrier counted-vmcnt ----------
// MODE 1: out bf16 at [B,H,Dh,T] from (m=h*64+d, n=bt), bias[m]   (V proj, pre-transposed)
// MODE 2: out fp32 row-major [M][N], bias[n]                      (final proj)
// MODE 3: fused Q+K: n<1024 -> Q (scaled), else K; out [B,H,T,Dh] x2
template<int MODE, int BM, int BN, int WM, int WN>
__global__ __launch_bounds__(512) void k_gemm2(
    const unsigned short* __restrict__ A,    // [M][K] bf16
    const unsigned short* __restrict__ Bt,   // [N][K] bf16
    const float* __restrict__ bias,
    const float* __restrict__ bias2,
    void* __restrict__ out, int M, int N, int K, float oscale)
{
  constexpr int TM = BM / WM, TN = BN / WN;   // per-wave output tile
  constexpr int MF = TM / 16, NF = TN / 16;   // fragment counts
  constexpr int AH = BM / 2,  BH = BN / 2;    // rows per LDS half
  __shared__ unsigned short As[2][2][AH * 64];
  __shared__ unsigned short Bs[2][2][BH * 64];

  const int t    = threadIdx.x;
  const int lane = t & 63;
  const int w    = t >> 6;                 // 0..7
  const int wm   = w / WN;
  const int wn   = w % WN;
  const int lr   = lane & 15;
  const int ck   = lane >> 4;              // 0..3
  const int rb   = ck << 2;

  // bijective XCD swizzle (nwg == 256, multiple of 8)
  const int gx  = gridDim.x;
  const int nwg = gx * gridDim.y;
  const int lid = blockIdx.y * gx + blockIdx.x;
  const int swz = (lid & 7) * (nwg >> 3) + (lid >> 3);
  const int n0  = (swz % gx) * BN;
  const int m0  = (swz / gx) * BM;

  // wave's read base within the half-tiles
  const int aHalf = (wm * TM) / AH, aBase = (wm * TM) % AH;
  const int bHalf = (wn * TN) / BH, bBase = (wn * TN) % BH;

  auto stgA = [&](int buf, int kt){
    #pragma unroll
    for (int ht = 0; ht < 2; ++ht)
      #pragma unroll
      for (int rr = 0; rr < AH / 64; ++rr){
        int u = t + rr * 512;
        int row = u >> 3, c = u & 7, cs = c ^ (row & 7);
        gload_lds16(A + (size_t)(m0 + ht * AH + row) * K + kt * 64 + cs * 8,
                    &As[buf][ht][u * 8]);
      }
  };
  auto stgB = [&](int buf, int kt){
    #pragma unroll
    for (int ht = 0; ht < 2; ++ht)
      #pragma unroll
      for (int rr = 0; rr < BH / 64; ++rr){
        int u = t + rr * 512;
        int row = u >> 3, c = u & 7, cs = c ^ (row & 7);
        gload_lds16(Bt + (size_t)(n0 + ht * BH + row) * K + kt * 64 + cs * 8,
                    &Bs[buf][ht][u * 8]);
      }
  };

  f32x4 acc[MF][NF];
  #pragma unroll
  for (int i = 0; i < MF; ++i)
    #pragma unroll
    for (int j = 0; j < NF; ++j) acc[i][j] = (f32x4){0.f, 0.f, 0.f, 0.f};

  const int NT = K >> 6;

  // prologue: both operands of kt=0
  stgA(0, 0); stgB(0, 0);

  for (int kt = 0; kt < NT; ++kt){
    const int cur = kt & 1;
    const unsigned short* Ah = &As[cur][aHalf][0];
    const unsigned short* Bh = &Bs[cur][bHalf][0];

    // ---- phase 0 (kh = 0) ----
    if (kt + 1 < NT){
      stgA(cur ^ 1, kt + 1);
      asm volatile("s_waitcnt vmcnt(%0)" :: "n"(BM / 64) : "memory");
    } else {
      asm volatile("s_waitcnt vmcnt(0)" ::: "memory");
    }
    __builtin_amdgcn_s_barrier();
    __builtin_amdgcn_sched_barrier(0);
    {
      bf16x8 af[MF], bfr[NF];
      #pragma unroll
      for (int i = 0; i < MF; ++i)
        af[i]  = *reinterpret_cast<const bf16x8*>(&Ah[(aBase + i * 16 + lr) * 64 + (ck ^ (lr & 7)) * 8]);
      #pragma unroll
      for (int i = 0; i < NF; ++i)
        bfr[i] = *reinterpret_cast<const bf16x8*>(&Bh[(bBase + i * 16 + lr) * 64 + (ck ^ (lr & 7)) * 8]);
      __builtin_amdgcn_s_setprio(1);
      #pragma unroll
      for (int mi = 0; mi < MF; ++mi)
        #pragma unroll
        for (int ni = 0; ni < NF; ++ni)
          acc[mi][ni] = __builtin_amdgcn_mfma_f32_16x16x32_bf16(af[mi], bfr[ni], acc[mi][ni], 0, 0, 0);
      __builtin_amdgcn_s_setprio(0);
    }

    // ---- phase 1 (kh = 1) ----
    if (kt + 1 < NT) stgB(cur ^ 1, kt + 1);
    {
      bf16x8 af[MF], bfr[NF];
      #pragma unroll
      for (int i = 0; i < MF; ++i)
        af[i]  = *reinterpret_cast<const bf16x8*>(&Ah[(aBase + i * 16 + lr) * 64 + ((4 + ck) ^ (lr & 7)) * 8]);
      #pragma unroll
      for (int i = 0; i < NF; ++i)
        bfr[i] = *reinterpret_cast<const bf16x8*>(&Bh[(bBase + i * 16 + lr) * 64 + ((4 + ck) ^ (lr & 7)) * 8]);
      __builtin_amdgcn_s_setprio(1);
      #pragma unroll
      for (int mi = 0; mi < MF; ++mi)
        #pragma unroll
        for (int ni = 0; ni < NF; ++ni)
          acc[mi][ni] = __builtin_amdgcn_mfma_f32_16x16x32_bf16(af[mi], bfr[ni], acc[mi][ni], 0, 0, 0);
      __builtin_amdgcn_s_setprio(0);
    }
    __builtin_amdgcn_s_barrier();
  }

  // ---------- epilogue ----------
  #pragma unroll
  for (int mf = 0; mf < MF; ++mf){
    #pragma unroll
    for (int ni = 0; ni < NF; ++ni){
      #pragma unroll
      for (int r = 0; r < 4; ++r){
        int m = m0 + wm * TM + mf * 16 + rb + r;
        int n = n0 + wn * TN + ni * 16 + lr;
        float v = acc[mf][ni][r];
        if (MODE == 1){
          v = (v + bias[m]) * oscale;
          int b = n >> 11, tt = n & 2047, h = m >> 6, d = m & 63;
          ((unsigned short*)out)[(((size_t)(b * 16 + h) * 64 + d) << 11) + tt] = f2bf(v);
        } else if (MODE == 2){
          v += bias[n];
          ((float*)out)[(size_t)m * N + n] = v;
        } else { // MODE 3: fused Q+K
          int seg = n >> 10, nn = n & 1023;
          v += seg ? bias2[nn] : bias[nn];
          if (!seg) v *= oscale;
          int b = m >> 11, tt = m & 2047, h = nn >> 6, d = nn & 63;
          ((unsigned short*)out)[(size_t)seg * BTOT * DM +
              (((size_t)(b * 16 + h) * 2048 + tt) << 6) + d] = f2bf(v);
        }
      }
    }
  }
}

// ---------- flash attention v10: 8-wave paired blocks, split PV accumulators ----------
// Grid (8, 64): block = 8 waves. Waves 0-3 -> q-tile blk, waves 4-7 -> 15-blk;
// ONE shared KV sweep serves both (balanced blocks; R12 lesson).
// R14 changes: (a) separate PV accumulators per 32-kv subtile (oA/oB, merged in
// epilogue) -> kb=0 and kb=1 chains fully independent, breaks the 8-deep
// chained-MFMA serializer; (b) NO setprio in the inner loop (side-effect instrs
// fence the scheduler; m190: setprio null/negative in barrier-lockstep blocks).
__global__ __launch_bounds__(512) void k_attn(
    const unsigned short* __restrict__ Qb,   // [B*H][T][64] bf16 (pre-scaled)
    const unsigned short* __restrict__ Kb,   // [B*H][T][64] bf16
    const unsigned short* __restrict__ Vt,   // [B*H][64][T] bf16
    unsigned short* __restrict__ Ya)         // [B*T][1024]  bf16
{
  __shared__ unsigned short Ks[2][64 * 64];   // 8 KB x2
  __shared__ unsigned short Vs[2][64 * 64];   // 8 KB x2

  const int t    = threadIdx.x;
  const int lane = t & 63;
  const int w    = t >> 6;                       // wave 0..7
  const int bh   = blockIdx.y;
  const int blk  = blockIdx.x;                   // pair index 0..7
  const int l31  = lane & 31;
  const int c2   = lane >> 5;

  const unsigned short* Qp = Qb + (size_t)bh * TSEQ * 64;
  const unsigned short* Kp = Kb + (size_t)bh * TSEQ * 64;
  const unsigned short* Vp = Vt + (size_t)bh * 64 * TSEQ;
  const int b = bh >> 4, h = bh & 15;

  const int qt   = (w >> 2) ? (15 - blk) : blk;  // this wave-group's q-tile
  const int q0   = qt * 128 + (w & 3) * 32;      // wave's first q-row
  const int wave_max = q0 + 31;
  const int ntiles   = 2 * (15 - blk) + 2;       // covers both q-tiles
  const int qrow = q0 + l31;                     // this lane's q-row

  // stage one 64-row K tile + V tile: 512 threads x (1 K + 1 V) = 2 loads/thread
  auto stage = [&](int buf, int kv0){
    int row = t >> 3, c = t & 7;
    int cs = c ^ (row & 7);
    gload_lds16(Kp + (size_t)(kv0 + row) * 64 + cs * 8, &Ks[buf][t * 8]);
    gload_lds16(Vp + (size_t)row * TSEQ + kv0 + cs * 8, &Vs[buf][t * 8]);
  };

  // Q as B-fragments: 4 k-windows of 16
  bf16x8 bQ[4];
  #pragma unroll
  for (int m = 0; m < 4; ++m)
    bQ[m] = *reinterpret_cast<const bf16x8*>(
        Qp + (size_t)qrow * 64 + m * 16 + c2 * 8);

  f32x16 oA[2] = {}, oB[2] = {};
  float l_part = 0.f;

  stage(0, 0);
  int cur = 0;

  for (int it = 0; it < ntiles; ++it){
    __builtin_amdgcn_sched_barrier(0);
    __builtin_amdgcn_s_barrier();              // barA: all waves done reading buf[cur^1]
    if (it + 1 < ntiles){
      stage(cur ^ 1, (it + 1) * 64);           // prefetch next tile
      asm volatile("s_waitcnt vmcnt(2)" ::: "memory");   // wait only current tile's loads
    } else {
      asm volatile("s_waitcnt vmcnt(0)" ::: "memory");
    }
    __builtin_amdgcn_s_barrier();              // barB: every wave's cur-loads landed
    __builtin_amdgcn_sched_barrier(0);

    const int kv0 = it * 64;
    #pragma unroll
    for (int kb = 0; kb < 2; ++kb){
      const int kvb = kv0 + kb * 32;
      if (kvb <= wave_max){
        // ---- S^T = K Q^T  (32 kv x 32 q), K as A, Q as B ----
        f32x16 st = {};
        #pragma unroll
        for (int m = 0; m < 4; ++m){
          int row = kb * 32 + l31;
          bf16x8 aK = *reinterpret_cast<const bf16x8*>(
              &Ks[cur][row * 64 + ((2 * m + c2) ^ (row & 7)) * 8]);
          st = __builtin_amdgcn_mfma_f32_32x32x16_bf16(aK, bQ[m], st, 0, 0, 0);
        }

        // ---- P = 2^(S^T) + causal zeroing (boundary sub-tiles only) ----
        const bool need_mask = (kvb + 31 > q0);
        float p[16];
        #pragma unroll
        for (int rg = 0; rg < 16; ++rg){
          float pv = exp2_raw(st[rg]);
          if (need_mask){
            int kv = kvb + 4 * c2 + 8 * (rg >> 2) + (rg & 3);
            pv = (kv > qrow) ? 0.f : pv;
          }
          p[rg] = pv;
        }
        // tree-sum into l_part
        {
          float s0 = (p[0] + p[1]) + (p[2] + p[3]);
          float s1 = (p[4] + p[5]) + (p[6] + p[7]);
          float s2 = (p[8] + p[9]) + (p[10] + p[11]);
          float s3 = (p[12] + p[13]) + (p[14] + p[15]);
          l_part += (s0 + s1) + (s2 + s3);
        }

        // ---- pack to bf16 + assemble PV A-frags via permlane32_swap ----
        unsigned pk[4][2];
        #pragma unroll
        for (int g = 0; g < 4; ++g){
          pk[g][0] = cvt_pk_bf16(p[g * 4 + 0], p[g * 4 + 1]);
          pk[g][1] = cvt_pk_bf16(p[g * 4 + 2], p[g * 4 + 3]);
        }
        f32x16* od = kb ? oB : oA;             // static per unrolled kb
        #pragma unroll
        for (int wl = 0; wl < 2; ++wl){
          u32x2 r0 = pl32swap(pk[2 * wl][0], pk[2 * wl + 1][0]);
          u32x2 r1 = pl32swap(pk[2 * wl][1], pk[2 * wl + 1][1]);
          union { unsigned u[4]; bf16x8 v; } ap;
          ap.u[0] = r0[0]; ap.u[1] = r1[0]; ap.u[2] = r0[1]; ap.u[3] = r1[1];
          const int wg = kb * 2 + wl;          // kv window of 16 within tile
          #pragma unroll
          for (int ntd = 0; ntd < 2; ++ntd){
            int row = ntd * 32 + l31;          // dh index
            bf16x8 bV = *reinterpret_cast<const bf16x8*>(
                &Vs[cur][row * 64 + ((2 * wg + c2) ^ (row & 7)) * 8]);
            od[ntd] = __builtin_amdgcn_mfma_f32_32x32x16_bf16(ap.v, bV, od[ntd], 0, 0, 0);
          }
        }
      }
    }
    cur ^= 1;
  }

  // ---- epilogue: merge split accumulators, reduce l, normalize, store ----
  float l_full = l_part + __shfl_xor(l_part, 32);
  float linv[16];
  #pragma unroll
  for (int rg = 0; rg < 16; ++rg){
    int qloc = 4 * c2 + 8 * (rg >> 2) + (rg & 3);
    linv[rg] = __builtin_amdgcn_rcpf(__shfl(l_full, qloc));
  }
  #pragma unroll
  for (int ntd = 0; ntd < 2; ++ntd)
    #pragma unroll
    for (int rg = 0; rg < 16; ++rg){
      int q = q0 + 4 * c2 + 8 * (rg >> 2) + (rg & 3);
      int d = ntd * 32 + l31;
      float v = (oA[ntd][rg] + oB[ntd][rg]) * linv[rg];
      Ya[((size_t)(b * 2048 + q)) * 1024 + h * 64 + d] = f2bf(v);
    }
}

extern "C" void kernel_launch(void* const* d_in, const int* in_sizes, int n_in,
                              void* d_out, int out_size, void* d_ws, size_t ws_size,
                              hipStream_t stream)
{
  const float* x  = (const float*)d_in[0];
  const float* Wq = (const float*)d_in[1];
  const float* bq = (const float*)d_in[2];
  const float* Wk = (const float*)d_in[3];
  const float* bk = (const float*)d_in[4];
  const float* Wv = (const float*)d_in[5];
  const float* bv = (const float*)d_in[6];
  const float* Wp = (const float*)d_in[7];
  const float* bp = (const float*)d_in[8];
  float* out = (float*)d_out;

  unsigned short* ws   = (unsigned short*)d_ws;
  unsigned short* x_bf = ws;                              // 8192*1024
  unsigned short* Wq_t = x_bf + (size_t)BTOT * DM;        // 1024*1024 each
  unsigned short* Wk_t = Wq_t + (size_t)DM * DM;          // contiguous after Wq_t
  unsigned short* Wv_t = Wk_t + (size_t)DM * DM;
  unsigned short* Wp_t = Wv_t + (size_t)DM * DM;
  unsigned short* Qb   = Wp_t + (size_t)DM * DM;          // 8192*1024
  unsigned short* Kb   = Qb   + (size_t)BTOT * DM;        // contiguous after Qb
  unsigned short* Vt   = Kb   + (size_t)BTOT * DM;
  unsigned short* Ya   = Vt   + (size_t)BTOT * DM;

  // softmax scale folded into Q: 1/sqrt(64) * log2(e)
  const float QSCALE = 0.125f * 1.44269504f;

  // fused prep: cast x (8192 blocks, full coverage) + transpose all 4 weights
  k_prep<<<8192 + 4096, 256, 0, stream>>>(
      x, x_bf, Wq, Wk, Wv, Wp, Wq_t, Wk_t, Wv_t, Wp_t);

  // fused Q+K: (x @ [Wq|Wk]) -> Qb, Kb  (256x256 tile, 256 blocks)
  k_gemm2<3, 256, 256, 2, 4><<<dim3(2048 / 256, BTOT / 256), 512, 0, stream>>>(
      x_bf, Wq_t, bq, bk, Qb, BTOT, 2048, DM, QSCALE);
  // V^T: Wv_t (M=1024) x x_bf (N=8192) -> [B,H,Dh,T]  (128x256 tile, 256 blocks)
  k_gemm2<1, 128, 256, 2, 4><<<dim3(BTOT / 256, DM / 128), 512, 0, stream>>>(
      Wv_t, x_bf, bv, nullptr, Vt, DM, BTOT, DM, 1.0f);

  k_attn<<<dim3(8, NB * NHEAD), 512, 0, stream>>>(Qb, Kb, Vt, Ya);

  // out-proj: Ya (M=8192) x Wp_t (N=1024) -> fp32  (256x128 tile, 256 blocks)
  k_gemm2<2, 256, 128, 4, 2><<<dim3(DM / 128, BTOT / 256), 512, 0, stream>>>(
      Ya, Wp_t, bp, nullptr, out, BTOT, DM, DM, 1.0f);
}

// Round 15
// 180.241 us; speedup vs baseline: 1.2047x; 1.2047x over previous
//
#include <hip/hip_runtime.h>
#include <hip/hip_bf16.h>
#include <stdint.h>

// Problem constants
#define TSEQ 2048
#define NB   4
#define NHEAD 16
#define HDIM 64
#define DM   1024
#define BTOT (NB*TSEQ)   // 8192 tokens

typedef __attribute__((ext_vector_type(8))) short bf16x8;   // 8 bf16 (4 VGPRs)
typedef __attribute__((ext_vector_type(4))) float f32x4;    // 16x16 MFMA C/D
typedef __attribute__((ext_vector_type(16))) float f32x16;  // 32x32 MFMA C/D
typedef __attribute__((ext_vector_type(2))) unsigned u32x2;

__device__ __forceinline__ unsigned short f2bf(float f){
  union { float f; unsigned u; } v; v.f = f;
  unsigned r = v.u + 0x7fffu + ((v.u >> 16) & 1u);   // RNE
  return (unsigned short)(r >> 16);
}

__device__ __forceinline__ unsigned cvt_pk_bf16(float lo, float hi){
  unsigned r;
  asm("v_cvt_pk_bf16_f32 %0, %1, %2" : "=v"(r) : "v"(lo), "v"(hi));
  return r;
}

// raw 2^x via compiler-aware intrinsic (R11-verified win vs exp2f libcall)
__device__ __forceinline__ float exp2_raw(float x){
#if __has_builtin(__builtin_amdgcn_exp2f)
  return __builtin_amdgcn_exp2f(x);
#else
  return exp2f(x);
#endif
}

__device__ __forceinline__ u32x2 pl32swap(unsigned a, unsigned b){
  auto r = __builtin_amdgcn_permlane32_swap((int)a, (int)b, false, false);
  return (u32x2){(unsigned)r[0], (unsigned)r[1]};
}

__device__ __forceinline__ void gload_lds16(const void* g, void* l){
  __builtin_amdgcn_global_load_lds(
      (const __attribute__((address_space(1))) void*)g,
      (__attribute__((address_space(3))) void*)l,
      16, 0, 0);
}

// ---------- fused prep: x cast (blocks 0..8191, FULL coverage) + 4 weight transposes ----------
__global__ __launch_bounds__(256) void k_prep(
    const float* __restrict__ x, unsigned short* __restrict__ x_bf,
    const float* __restrict__ Wq, const float* __restrict__ Wk,
    const float* __restrict__ Wv, const float* __restrict__ Wp,
    unsigned short* __restrict__ Wq_t, unsigned short* __restrict__ Wk_t,
    unsigned short* __restrict__ Wv_t, unsigned short* __restrict__ Wp_t)
{
  __shared__ unsigned short tile_s[32][33];
  const int bid = blockIdx.x;
  if (bid < 8192){
    size_t j = ((size_t)bid * 256 + threadIdx.x) * 4;
    float4 v = *reinterpret_cast<const float4*>(x + j);
    unsigned long long pk =  (unsigned long long)f2bf(v.x)
                          | ((unsigned long long)f2bf(v.y) << 16)
                          | ((unsigned long long)f2bf(v.z) << 32)
                          | ((unsigned long long)f2bf(v.w) << 48);
    *reinterpret_cast<unsigned long long*>(x_bf + j) = pk;
  } else {
    const int r   = bid - 8192;
    const int job = r >> 10, tile = r & 1023;
    const float* W = (job == 0) ? Wq : (job == 1) ? Wk : (job == 2) ? Wv : Wp;
    unsigned short* Wt = (job == 0) ? Wq_t : (job == 1) ? Wk_t : (job == 2) ? Wv_t : Wp_t;
    const int n0 = (tile & 31) * 32, k0 = (tile >> 5) * 32;
    const int tx = threadIdx.x & 31, ty = threadIdx.x >> 5;   // 32 x 8
    #pragma unroll
    for (int j = ty; j < 32; j += 8)
      tile_s[j][tx] = f2bf(W[(size_t)(k0 + j) * DM + n0 + tx]);
    __syncthreads();
    #pragma unroll
    for (int j = ty; j < 32; j += 8)
      Wt[(size_t)(n0 + j) * DM + k0 + tx] = tile_s[tx][j];
  }
}

// ---------- bf16 GEMM v3: templated tile, BK=64, 8 waves, 2-barrier counted-vmcnt ----------
// MODE 1: out bf16 at [B,H,Dh,T] from (m=h*64+d, n=bt), bias[m]   (V proj, pre-transposed)
// MODE 2: out fp32 row-major [M][N], bias[n]                      (final proj)
// MODE 3: fused Q+K: n<1024 -> Q (scaled), else K; out [B,H,T,Dh] x2
template<int MODE, int BM, int BN, int WM, int WN>
__global__ __launch_bounds__(512) void k_gemm2(
    const unsigned short* __restrict__ A,    // [M][K] bf16
    const unsigned short* __restrict__ Bt,   // [N][K] bf16
    const float* __restrict__ bias,
    const float* __restrict__ bias2,
    void* __restrict__ out, int M, int N, int K, float oscale)
{
  constexpr int TM = BM / WM, TN = BN / WN;   // per-wave output tile
  constexpr int MF = TM / 16, NF = TN / 16;   // fragment counts
  constexpr int AH = BM / 2,  BH = BN / 2;    // rows per LDS half
  __shared__ unsigned short As[2][2][AH * 64];
  __shared__ unsigned short Bs[2][2][BH * 64];

  const int t    = threadIdx.x;
  const int lane = t & 63;
  const int w    = t >> 6;                 // 0..7
  const int wm   = w / WN;
  const int wn   = w % WN;
  const int lr   = lane & 15;
  const int ck   = lane >> 4;              // 0..3
  const int rb   = ck << 2;

  // bijective XCD swizzle (nwg == 256, multiple of 8)
  const int gx  = gridDim.x;
  const int nwg = gx * gridDim.y;
  const int lid = blockIdx.y * gx + blockIdx.x;
  const int swz = (lid & 7) * (nwg >> 3) + (lid >> 3);
  const int n0  = (swz % gx) * BN;
  const int m0  = (swz / gx) * BM;

  // wave's read base within the half-tiles
  const int aHalf = (wm * TM) / AH, aBase = (wm * TM) % AH;
  const int bHalf = (wn * TN) / BH, bBase = (wn * TN) % BH;

  auto stgA = [&](int buf, int kt){
    #pragma unroll
    for (int ht = 0; ht < 2; ++ht)
      #pragma unroll
      for (int rr = 0; rr < AH / 64; ++rr){
        int u = t + rr * 512;
        int row = u >> 3, c = u & 7, cs = c ^ (row & 7);
        gload_lds16(A + (size_t)(m0 + ht * AH + row) * K + kt * 64 + cs * 8,
                    &As[buf][ht][u * 8]);
      }
  };
  auto stgB = [&](int buf, int kt){
    #pragma unroll
    for (int ht = 0; ht < 2; ++ht)
      #pragma unroll
      for (int rr = 0; rr < BH / 64; ++rr){
        int u = t + rr * 512;
        int row = u >> 3, c = u & 7, cs = c ^ (row & 7);
        gload_lds16(Bt + (size_t)(n0 + ht * BH + row) * K + kt * 64 + cs * 8,
                    &Bs[buf][ht][u * 8]);
      }
  };

  f32x4 acc[MF][NF];
  #pragma unroll
  for (int i = 0; i < MF; ++i)
    #pragma unroll
    for (int j = 0; j < NF; ++j) acc[i][j] = (f32x4){0.f, 0.f, 0.f, 0.f};

  const int NT = K >> 6;

  // prologue: both operands of kt=0
  stgA(0, 0); stgB(0, 0);

  for (int kt = 0; kt < NT; ++kt){
    const int cur = kt & 1;
    const unsigned short* Ah = &As[cur][aHalf][0];
    const unsigned short* Bh = &Bs[cur][bHalf][0];

    // ---- phase 0 (kh = 0) ----
    if (kt + 1 < NT){
      stgA(cur ^ 1, kt + 1);
      asm volatile("s_waitcnt vmcnt(%0)" :: "n"(BM / 64) : "memory");
    } else {
      asm volatile("s_waitcnt vmcnt(0)" ::: "memory");
    }
    __builtin_amdgcn_s_barrier();
    __builtin_amdgcn_sched_barrier(0);
    {
      bf16x8 af[MF], bfr[NF];
      #pragma unroll
      for (int i = 0; i < MF; ++i)
        af[i]  = *reinterpret_cast<const bf16x8*>(&Ah[(aBase + i * 16 + lr) * 64 + (ck ^ (lr & 7)) * 8]);
      #pragma unroll
      for (int i = 0; i < NF; ++i)
        bfr[i] = *reinterpret_cast<const bf16x8*>(&Bh[(bBase + i * 16 + lr) * 64 + (ck ^ (lr & 7)) * 8]);
      __builtin_amdgcn_s_setprio(1);
      #pragma unroll
      for (int mi = 0; mi < MF; ++mi)
        #pragma unroll
        for (int ni = 0; ni < NF; ++ni)
          acc[mi][ni] = __builtin_amdgcn_mfma_f32_16x16x32_bf16(af[mi], bfr[ni], acc[mi][ni], 0, 0, 0);
      __builtin_amdgcn_s_setprio(0);
    }

    // ---- phase 1 (kh = 1) ----
    if (kt + 1 < NT) stgB(cur ^ 1, kt + 1);
    {
      bf16x8 af[MF], bfr[NF];
      #pragma unroll
      for (int i = 0; i < MF; ++i)
        af[i]  = *reinterpret_cast<const bf16x8*>(&Ah[(aBase + i * 16 + lr) * 64 + ((4 + ck) ^ (lr & 7)) * 8]);
      #pragma unroll
      for (int i = 0; i < NF; ++i)
        bfr[i] = *reinterpret_cast<const bf16x8*>(&Bh[(bBase + i * 16 + lr) * 64 + ((4 + ck) ^ (lr & 7)) * 8]);
      __builtin_amdgcn_s_setprio(1);
      #pragma unroll
      for (int mi = 0; mi < MF; ++mi)
        #pragma unroll
        for (int ni = 0; ni < NF; ++ni)
          acc[mi][ni] = __builtin_amdgcn_mfma_f32_16x16x32_bf16(af[mi], bfr[ni], acc[mi][ni], 0, 0, 0);
      __builtin_amdgcn_s_setprio(0);
    }
    __builtin_amdgcn_s_barrier();
  }

  // ---------- epilogue ----------
  #pragma unroll
  for (int mf = 0; mf < MF; ++mf){
    #pragma unroll
    for (int ni = 0; ni < NF; ++ni){
      #pragma unroll
      for (int r = 0; r < 4; ++r){
        int m = m0 + wm * TM + mf * 16 + rb + r;
        int n = n0 + wn * TN + ni * 16 + lr;
        float v = acc[mf][ni][r];
        if (MODE == 1){
          v = (v + bias[m]) * oscale;
          int b = n >> 11, tt = n & 2047, h = m >> 6, d = m & 63;
          ((unsigned short*)out)[(((size_t)(b * 16 + h) * 64 + d) << 11) + tt] = f2bf(v);
        } else if (MODE == 2){
          v += bias[n];
          ((float*)out)[(size_t)m * N + n] = v;
        } else { // MODE 3: fused Q+K
          int seg = n >> 10, nn = n & 1023;
          v += seg ? bias2[nn] : bias[nn];
          if (!seg) v *= oscale;
          int b = m >> 11, tt = m & 2047, h = nn >> 6, d = nn & 63;
          ((unsigned short*)out)[(size_t)seg * BTOT * DM +
              (((size_t)(b * 16 + h) * 2048 + tt) << 6) + d] = f2bf(v);
        }
      }
    }
  }
}

// ---------- flash attention v11: 8-wave paired blocks, NAMED split PV accumulators ----------
// = R13 structure (setprio kept, counted-vmcnt loop) + split accumulators done
// right: PV body is a macro expanded per kb with a NAMED accumulator array
// (R14's runtime pointer `kb ? oB : oA` sent the accumulators to scratch —
// rule #20 class; VGPR dropped to 72 and everything stalled on scratch).
#define ATTN_PV(OD, KB)                                                        \
  {                                                                            \
    unsigned pk0a = cvt_pk_bf16(p[0],  p[1]);                                  \
    unsigned pk0b = cvt_pk_bf16(p[2],  p[3]);                                  \
    unsigned pk1a = cvt_pk_bf16(p[4],  p[5]);                                  \
    unsigned pk1b = cvt_pk_bf16(p[6],  p[7]);                                  \
    unsigned pk2a = cvt_pk_bf16(p[8],  p[9]);                                  \
    unsigned pk2b = cvt_pk_bf16(p[10], p[11]);                                 \
    unsigned pk3a = cvt_pk_bf16(p[12], p[13]);                                 \
    unsigned pk3b = cvt_pk_bf16(p[14], p[15]);                                 \
    __builtin_amdgcn_s_setprio(1);                                             \
    {                                                                          \
      u32x2 r0 = pl32swap(pk0a, pk1a);                                         \
      u32x2 r1 = pl32swap(pk0b, pk1b);                                         \
      union { unsigned u[4]; bf16x8 v; } ap;                                   \
      ap.u[0] = r0[0]; ap.u[1] = r1[0]; ap.u[2] = r0[1]; ap.u[3] = r1[1];      \
      const int wg = (KB) * 2;                                                 \
      _Pragma("unroll")                                                        \
      for (int ntd = 0; ntd < 2; ++ntd){                                       \
        int row = ntd * 32 + l31;                                              \
        bf16x8 bV = *reinterpret_cast<const bf16x8*>(                          \
            &Vs[cur][row * 64 + ((2 * wg + c2) ^ (row & 7)) * 8]);             \
        OD[ntd] = __builtin_amdgcn_mfma_f32_32x32x16_bf16(ap.v, bV, OD[ntd], 0, 0, 0); \
      }                                                                        \
    }                                                                          \
    {                                                                          \
      u32x2 r0 = pl32swap(pk2a, pk3a);                                         \
      u32x2 r1 = pl32swap(pk2b, pk3b);                                         \
      union { unsigned u[4]; bf16x8 v; } ap;                                   \
      ap.u[0] = r0[0]; ap.u[1] = r1[0]; ap.u[2] = r0[1]; ap.u[3] = r1[1];      \
      const int wg = (KB) * 2 + 1;                                             \
      _Pragma("unroll")                                                        \
      for (int ntd = 0; ntd < 2; ++ntd){                                       \
        int row = ntd * 32 + l31;                                              \
        bf16x8 bV = *reinterpret_cast<const bf16x8*>(                          \
            &Vs[cur][row * 64 + ((2 * wg + c2) ^ (row & 7)) * 8]);             \
        OD[ntd] = __builtin_amdgcn_mfma_f32_32x32x16_bf16(ap.v, bV, OD[ntd], 0, 0, 0); \
      }                                                                        \
    }                                                                          \
    __builtin_amdgcn_s_setprio(0);                                             \
  }

#define ATTN_SUBTILE(OD, KB)                                                   \
  {                                                                            \
    const int kvb = kv0 + (KB) * 32;                                           \
    if (kvb <= wave_max){                                                      \
      f32x16 st = {};                                                          \
      __builtin_amdgcn_s_setprio(1);                                           \
      _Pragma("unroll")                                                        \
      for (int m = 0; m < 4; ++m){                                             \
        int row = (KB) * 32 + l31;                                             \
        bf16x8 aK = *reinterpret_cast<const bf16x8*>(                          \
            &Ks[cur][row * 64 + ((2 * m + c2) ^ (row & 7)) * 8]);              \
        st = __builtin_amdgcn_mfma_f32_32x32x16_bf16(aK, bQ[m], st, 0, 0, 0);  \
      }                                                                        \
      __builtin_amdgcn_s_setprio(0);                                           \
      const bool need_mask = (kvb + 31 > q0);                                  \
      float p[16];                                                             \
      _Pragma("unroll")                                                        \
      for (int rg = 0; rg < 16; ++rg){                                         \
        float pv = exp2_raw(st[rg]);                                           \
        if (need_mask){                                                        \
          int kv = kvb + 4 * c2 + 8 * (rg >> 2) + (rg & 3);                    \
          pv = (kv > qrow) ? 0.f : pv;                                         \
        }                                                                      \
        p[rg] = pv;                                                            \
      }                                                                        \
      {                                                                        \
        float s0 = (p[0] + p[1]) + (p[2] + p[3]);                              \
        float s1 = (p[4] + p[5]) + (p[6] + p[7]);                              \
        float s2 = (p[8] + p[9]) + (p[10] + p[11]);                            \
        float s3 = (p[12] + p[13]) + (p[14] + p[15]);                          \
        l_part += (s0 + s1) + (s2 + s3);                                       \
      }                                                                        \
      ATTN_PV(OD, KB)                                                          \
    }                                                                          \
  }

__global__ __launch_bounds__(512) void k_attn(
    const unsigned short* __restrict__ Qb,   // [B*H][T][64] bf16 (pre-scaled)
    const unsigned short* __restrict__ Kb,   // [B*H][T][64] bf16
    const unsigned short* __restrict__ Vt,   // [B*H][64][T] bf16
    unsigned short* __restrict__ Ya)         // [B*T][1024]  bf16
{
  __shared__ unsigned short Ks[2][64 * 64];   // 8 KB x2
  __shared__ unsigned short Vs[2][64 * 64];   // 8 KB x2

  const int t    = threadIdx.x;
  const int lane = t & 63;
  const int w    = t >> 6;                       // wave 0..7
  const int bh   = blockIdx.y;
  const int blk  = blockIdx.x;                   // pair index 0..7
  const int l31  = lane & 31;
  const int c2   = lane >> 5;

  const unsigned short* Qp = Qb + (size_t)bh * TSEQ * 64;
  const unsigned short* Kp = Kb + (size_t)bh * TSEQ * 64;
  const unsigned short* Vp = Vt + (size_t)bh * 64 * TSEQ;
  const int b = bh >> 4, h = bh & 15;

  const int qt   = (w >> 2) ? (15 - blk) : blk;  // this wave-group's q-tile
  const int q0   = qt * 128 + (w & 3) * 32;      // wave's first q-row
  const int wave_max = q0 + 31;
  const int ntiles   = 2 * (15 - blk) + 2;       // covers both q-tiles
  const int qrow = q0 + l31;                     // this lane's q-row

  // stage one 64-row K tile + V tile: 512 threads x (1 K + 1 V) = 2 loads/thread
  auto stage = [&](int buf, int kv0){
    int row = t >> 3, c = t & 7;
    int cs = c ^ (row & 7);
    gload_lds16(Kp + (size_t)(kv0 + row) * 64 + cs * 8, &Ks[buf][t * 8]);
    gload_lds16(Vp + (size_t)row * TSEQ + kv0 + cs * 8, &Vs[buf][t * 8]);
  };

  // Q as B-fragments: 4 k-windows of 16
  bf16x8 bQ[4];
  #pragma unroll
  for (int m = 0; m < 4; ++m)
    bQ[m] = *reinterpret_cast<const bf16x8*>(
        Qp + (size_t)qrow * 64 + m * 16 + c2 * 8);

  f32x16 oA[2] = {}, oB[2] = {};
  float l_part = 0.f;

  stage(0, 0);
  int cur = 0;

  for (int it = 0; it < ntiles; ++it){
    __builtin_amdgcn_sched_barrier(0);
    __builtin_amdgcn_s_barrier();              // barA: all waves done reading buf[cur^1]
    if (it + 1 < ntiles){
      stage(cur ^ 1, (it + 1) * 64);           // prefetch next tile
      asm volatile("s_waitcnt vmcnt(2)" ::: "memory");   // wait only current tile's loads
    } else {
      asm volatile("s_waitcnt vmcnt(0)" ::: "memory");
    }
    __builtin_amdgcn_s_barrier();              // barB: every wave's cur-loads landed
    __builtin_amdgcn_sched_barrier(0);

    const int kv0 = it * 64;
    ATTN_SUBTILE(oA, 0)
    ATTN_SUBTILE(oB, 1)
    cur ^= 1;
  }

  // ---- epilogue: merge split accumulators, reduce l, normalize, store ----
  float l_full = l_part + __shfl_xor(l_part, 32);
  float linv[16];
  #pragma unroll
  for (int rg = 0; rg < 16; ++rg){
    int qloc = 4 * c2 + 8 * (rg >> 2) + (rg & 3);
    linv[rg] = __builtin_amdgcn_rcpf(__shfl(l_full, qloc));
  }
  #pragma unroll
  for (int ntd = 0; ntd < 2; ++ntd)
    #pragma unroll
    for (int rg = 0; rg < 16; ++rg){
      int q = q0 + 4 * c2 + 8 * (rg >> 2) + (rg & 3);
      int d = ntd * 32 + l31;
      float v = (oA[ntd][rg] + oB[ntd][rg]) * linv[rg];
      Ya[((size_t)(b * 2048 + q)) * 1024 + h * 64 + d] = f2bf(v);
    }
}

extern "C" void kernel_launch(void* const* d_in, const int* in_sizes, int n_in,
                              void* d_out, int out_size, void* d_ws, size_t ws_size,
                              hipStream_t stream)
{
  const float* x  = (const float*)d_in[0];
  const float* Wq = (const float*)d_in[1];
  const float* bq = (const float*)d_in[2];
  const float* Wk = (const float*)d_in[3];
  const float* bk = (const float*)d_in[4];
  const float* Wv = (const float*)d_in[5];
  const float* bv = (const float*)d_in[6];
  const float* Wp = (const float*)d_in[7];
  const float* bp = (const float*)d_in[8];
  float* out = (float*)d_out;

  unsigned short* ws   = (unsigned short*)d_ws;
  unsigned short* x_bf = ws;                              // 8192*1024
  unsigned short* Wq_t = x_bf + (size_t)BTOT * DM;        // 1024*1024 each
  unsigned short* Wk_t = Wq_t + (size_t)DM * DM;          // contiguous after Wq_t
  unsigned short* Wv_t = Wk_t + (size_t)DM * DM;
  unsigned short* Wp_t = Wv_t + (size_t)DM * DM;
  unsigned short* Qb   = Wp_t + (size_t)DM * DM;          // 8192*1024
  unsigned short* Kb   = Qb   + (size_t)BTOT * DM;        // contiguous after Qb
  unsigned short* Vt   = Kb   + (size_t)BTOT * DM;
  unsigned short* Ya   = Vt   + (size_t)BTOT * DM;

  // softmax scale folded into Q: 1/sqrt(64) * log2(e)
  const float QSCALE = 0.125f * 1.44269504f;

  // fused prep: cast x (8192 blocks, full coverage) + transpose all 4 weights
  k_prep<<<8192 + 4096, 256, 0, stream>>>(
      x, x_bf, Wq, Wk, Wv, Wp, Wq_t, Wk_t, Wv_t, Wp_t);

  // fused Q+K: (x @ [Wq|Wk]) -> Qb, Kb  (256x256 tile, 256 blocks)
  k_gemm2<3, 256, 256, 2, 4><<<dim3(2048 / 256, BTOT / 256), 512, 0, stream>>>(
      x_bf, Wq_t, bq, bk, Qb, BTOT, 2048, DM, QSCALE);
  // V^T: Wv_t (M=1024) x x_bf (N=8192) -> [B,H,Dh,T]  (128x256 tile, 256 blocks)
  k_gemm2<1, 128, 256, 2, 4><<<dim3(BTOT / 256, DM / 128), 512, 0, stream>>>(
      Wv_t, x_bf, bv, nullptr, Vt, DM, BTOT, DM, 1.0f);

  k_attn<<<dim3(8, NB * NHEAD), 512, 0, stream>>>(Qb, Kb, Vt, Ya);

  // out-proj: Ya (M=8192) x Wp_t (N=1024) -> fp32  (256x128 tile, 256 blocks)
  k_gemm2<2, 256, 128, 4, 2><<<dim3(DM / 128, BTOT / 256), 512, 0, stream>>>(
      Ya, Wp_t, bp, nullptr, out, BTOT, DM, DM, 1.0f);
}

// Round 16
// 175.088 us; speedup vs baseline: 1.2402x; 1.0294x over previous
//
#include <hip/hip_runtime.h>
#include <hip/hip_bf16.h>
#include <stdint.h>

// Problem constants
#define TSEQ 2048
#define NB   4
#define NHEAD 16
#define HDIM 64
#define DM   1024
#define BTOT (NB*TSEQ)   // 8192 tokens

typedef __attribute__((ext_vector_type(8))) short bf16x8;   // 8 bf16 (4 VGPRs)
typedef __attribute__((ext_vector_type(4))) float f32x4;    // 16x16 MFMA C/D
typedef __attribute__((ext_vector_type(16))) float f32x16;  // 32x32 MFMA C/D
typedef __attribute__((ext_vector_type(2))) unsigned u32x2;

__device__ __forceinline__ unsigned short f2bf(float f){
  union { float f; unsigned u; } v; v.f = f;
  unsigned r = v.u + 0x7fffu + ((v.u >> 16) & 1u);   // RNE
  return (unsigned short)(r >> 16);
}

__device__ __forceinline__ unsigned cvt_pk_bf16(float lo, float hi){
  unsigned r;
  asm("v_cvt_pk_bf16_f32 %0, %1, %2" : "=v"(r) : "v"(lo), "v"(hi));
  return r;
}

// raw 2^x via compiler-aware intrinsic (R11-verified win vs exp2f libcall)
__device__ __forceinline__ float exp2_raw(float x){
#if __has_builtin(__builtin_amdgcn_exp2f)
  return __builtin_amdgcn_exp2f(x);
#else
  return exp2f(x);
#endif
}

__device__ __forceinline__ u32x2 pl32swap(unsigned a, unsigned b){
  auto r = __builtin_amdgcn_permlane32_swap((int)a, (int)b, false, false);
  return (u32x2){(unsigned)r[0], (unsigned)r[1]};
}

__device__ __forceinline__ void gload_lds16(const void* g, void* l){
  __builtin_amdgcn_global_load_lds(
      (const __attribute__((address_space(1))) void*)g,
      (__attribute__((address_space(3))) void*)l,
      16, 0, 0);
}

// ---------- fused prep: x cast (blocks 0..8191, FULL coverage) + 4 weight transposes ----------
__global__ __launch_bounds__(256) void k_prep(
    const float* __restrict__ x, unsigned short* __restrict__ x_bf,
    const float* __restrict__ Wq, const float* __restrict__ Wk,
    const float* __restrict__ Wv, const float* __restrict__ Wp,
    unsigned short* __restrict__ Wq_t, unsigned short* __restrict__ Wk_t,
    unsigned short* __restrict__ Wv_t, unsigned short* __restrict__ Wp_t)
{
  __shared__ unsigned short tile_s[32][33];
  const int bid = blockIdx.x;
  if (bid < 8192){
    size_t j = ((size_t)bid * 256 + threadIdx.x) * 4;
    float4 v = *reinterpret_cast<const float4*>(x + j);
    unsigned long long pk =  (unsigned long long)f2bf(v.x)
                          | ((unsigned long long)f2bf(v.y) << 16)
                          | ((unsigned long long)f2bf(v.z) << 32)
                          | ((unsigned long long)f2bf(v.w) << 48);
    *reinterpret_cast<unsigned long long*>(x_bf + j) = pk;
  } else {
    const int r   = bid - 8192;
    const int job = r >> 10, tile = r & 1023;
    const float* W = (job == 0) ? Wq : (job == 1) ? Wk : (job == 2) ? Wv : Wp;
    unsigned short* Wt = (job == 0) ? Wq_t : (job == 1) ? Wk_t : (job == 2) ? Wv_t : Wp_t;
    const int n0 = (tile & 31) * 32, k0 = (tile >> 5) * 32;
    const int tx = threadIdx.x & 31, ty = threadIdx.x >> 5;   // 32 x 8
    #pragma unroll
    for (int j = ty; j < 32; j += 8)
      tile_s[j][tx] = f2bf(W[(size_t)(k0 + j) * DM + n0 + tx]);
    __syncthreads();
    #pragma unroll
    for (int j = ty; j < 32; j += 8)
      Wt[(size_t)(n0 + j) * DM + k0 + tx] = tile_s[tx][j];
  }
}

// ---------- bf16 GEMM v4: templated tile, BK=64, 8 waves, 4-phase quadrant schedule ----------
// (T3+T4 port of the verified 8-phase template: per K-tile 4 quadrant-phases
// (mh,kh), each {ds_read subtile ∥ stage-issue ∥ barrier; lgkmcnt(0)+
// sched_barrier (rule #18); setprio MFMA cluster; barrier}. stgA issued at ph0,
// stgB at ph1 -> loads stay in flight across ~6 barriers under 3 phases of
// MFMA cover; buffer drain vmcnt(0) ONLY at end of ph3 (double-buffer depth-1).
// B-fragments reused across mh-phases (half the LDS reads).
// MODE 1: out bf16 at [B,H,Dh,T] from (m=h*64+d, n=bt), bias[m]   (V proj)
// MODE 2: out fp32 row-major [M][N], bias[n]                      (final proj)
// MODE 3: fused Q+K: n<1024 -> Q (scaled), else K; out [B,H,T,Dh] x2
template<int MODE, int BM, int BN, int WM, int WN>
__global__ __launch_bounds__(512) void k_gemm2(
    const unsigned short* __restrict__ A,    // [M][K] bf16
    const unsigned short* __restrict__ Bt,   // [N][K] bf16
    const float* __restrict__ bias,
    const float* __restrict__ bias2,
    void* __restrict__ out, int M, int N, int K, float oscale)
{
  constexpr int TM = BM / WM, TN = BN / WN;   // per-wave output tile
  constexpr int MF = TM / 16, NF = TN / 16;   // fragment counts
  constexpr int MH = MF / 2;                  // m-half fragment count
  constexpr int AH = BM / 2,  BH = BN / 2;    // rows per LDS half
  __shared__ unsigned short As[2][2][AH * 64];
  __shared__ unsigned short Bs[2][2][BH * 64];

  const int t    = threadIdx.x;
  const int lane = t & 63;
  const int w    = t >> 6;                 // 0..7
  const int wm   = w / WN;
  const int wn   = w % WN;
  const int lr   = lane & 15;
  const int ck   = lane >> 4;              // 0..3
  const int rb   = ck << 2;

  // bijective XCD swizzle (nwg == 256, multiple of 8)
  const int gx  = gridDim.x;
  const int nwg = gx * gridDim.y;
  const int lid = blockIdx.y * gx + blockIdx.x;
  const int swz = (lid & 7) * (nwg >> 3) + (lid >> 3);
  const int n0  = (swz % gx) * BN;
  const int m0  = (swz / gx) * BM;

  // wave's read base within the half-tiles
  const int aHalf = (wm * TM) / AH, aBase = (wm * TM) % AH;
  const int bHalf = (wn * TN) / BH, bBase = (wn * TN) % BH;

  auto stgA = [&](int buf, int kt){
    #pragma unroll
    for (int ht = 0; ht < 2; ++ht)
      #pragma unroll
      for (int rr = 0; rr < AH / 64; ++rr){
        int u = t + rr * 512;
        int row = u >> 3, c = u & 7, cs = c ^ (row & 7);
        gload_lds16(A + (size_t)(m0 + ht * AH + row) * K + kt * 64 + cs * 8,
                    &As[buf][ht][u * 8]);
      }
  };
  auto stgB = [&](int buf, int kt){
    #pragma unroll
    for (int ht = 0; ht < 2; ++ht)
      #pragma unroll
      for (int rr = 0; rr < BH / 64; ++rr){
        int u = t + rr * 512;
        int row = u >> 3, c = u & 7, cs = c ^ (row & 7);
        gload_lds16(Bt + (size_t)(n0 + ht * BH + row) * K + kt * 64 + cs * 8,
                    &Bs[buf][ht][u * 8]);
      }
  };

  f32x4 acc[MF][NF];
  #pragma unroll
  for (int i = 0; i < MF; ++i)
    #pragma unroll
    for (int j = 0; j < NF; ++j) acc[i][j] = (f32x4){0.f, 0.f, 0.f, 0.f};

  const int NT = K >> 6;

  // prologue: both operands of kt=0, drained + visible before first reads
  stgA(0, 0); stgB(0, 0);
  asm volatile("s_waitcnt vmcnt(0)" ::: "memory");
  __builtin_amdgcn_s_barrier();

  for (int kt = 0; kt < NT; ++kt){
    const int cur = kt & 1;
    const unsigned short* Ah = &As[cur][aHalf][0];
    const unsigned short* Bh = &Bs[cur][bHalf][0];
    bf16x8 af[MH], bfr[NF];

    // ---- phase 0: quadrant (mh=0, kh=0); issue stgA(kt+1) ----
    #pragma unroll
    for (int i = 0; i < MH; ++i)
      af[i]  = *reinterpret_cast<const bf16x8*>(&Ah[(aBase + i * 16 + lr) * 64 + (ck ^ (lr & 7)) * 8]);
    #pragma unroll
    for (int i = 0; i < NF; ++i)
      bfr[i] = *reinterpret_cast<const bf16x8*>(&Bh[(bBase + i * 16 + lr) * 64 + (ck ^ (lr & 7)) * 8]);
    if (kt + 1 < NT) stgA(cur ^ 1, kt + 1);
    __builtin_amdgcn_s_barrier();
    asm volatile("s_waitcnt lgkmcnt(0)" ::: "memory");
    __builtin_amdgcn_sched_barrier(0);
    __builtin_amdgcn_s_setprio(1);
    #pragma unroll
    for (int mi = 0; mi < MH; ++mi)
      #pragma unroll
      for (int ni = 0; ni < NF; ++ni)
        acc[mi][ni] = __builtin_amdgcn_mfma_f32_16x16x32_bf16(af[mi], bfr[ni], acc[mi][ni], 0, 0, 0);
    __builtin_amdgcn_s_setprio(0);
    __builtin_amdgcn_s_barrier();

    // ---- phase 1: quadrant (mh=1, kh=0); issue stgB(kt+1); bfr reused ----
    #pragma unroll
    for (int i = 0; i < MH; ++i)
      af[i]  = *reinterpret_cast<const bf16x8*>(&Ah[(aBase + (MH + i) * 16 + lr) * 64 + (ck ^ (lr & 7)) * 8]);
    if (kt + 1 < NT) stgB(cur ^ 1, kt + 1);
    __builtin_amdgcn_s_barrier();
    asm volatile("s_waitcnt lgkmcnt(0)" ::: "memory");
    __builtin_amdgcn_sched_barrier(0);
    __builtin_amdgcn_s_setprio(1);
    #pragma unroll
    for (int mi = 0; mi < MH; ++mi)
      #pragma unroll
      for (int ni = 0; ni < NF; ++ni)
        acc[MH + mi][ni] = __builtin_amdgcn_mfma_f32_16x16x32_bf16(af[mi], bfr[ni], acc[MH + mi][ni], 0, 0, 0);
    __builtin_amdgcn_s_setprio(0);
    __builtin_amdgcn_s_barrier();

    // ---- phase 2: quadrant (mh=0, kh=1) ----
    #pragma unroll
    for (int i = 0; i < MH; ++i)
      af[i]  = *reinterpret_cast<const bf16x8*>(&Ah[(aBase + i * 16 + lr) * 64 + ((4 + ck) ^ (lr & 7)) * 8]);
    #pragma unroll
    for (int i = 0; i < NF; ++i)
      bfr[i] = *reinterpret_cast<const bf16x8*>(&Bh[(bBase + i * 16 + lr) * 64 + ((4 + ck) ^ (lr & 7)) * 8]);
    __builtin_amdgcn_s_barrier();
    asm volatile("s_waitcnt lgkmcnt(0)" ::: "memory");
    __builtin_amdgcn_sched_barrier(0);
    __builtin_amdgcn_s_setprio(1);
    #pragma unroll
    for (int mi = 0; mi < MH; ++mi)
      #pragma unroll
      for (int ni = 0; ni < NF; ++ni)
        acc[mi][ni] = __builtin_amdgcn_mfma_f32_16x16x32_bf16(af[mi], bfr[ni], acc[mi][ni], 0, 0, 0);
    __builtin_amdgcn_s_setprio(0);
    __builtin_amdgcn_s_barrier();

    // ---- phase 3: quadrant (mh=1, kh=1); end-of-tile drain ----
    #pragma unroll
    for (int i = 0; i < MH; ++i)
      af[i]  = *reinterpret_cast<const bf16x8*>(&Ah[(aBase + (MH + i) * 16 + lr) * 64 + ((4 + ck) ^ (lr & 7)) * 8]);
    __builtin_amdgcn_s_barrier();
    asm volatile("s_waitcnt lgkmcnt(0)" ::: "memory");
    __builtin_amdgcn_sched_barrier(0);
    __builtin_amdgcn_s_setprio(1);
    #pragma unroll
    for (int mi = 0; mi < MH; ++mi)
      #pragma unroll
      for (int ni = 0; ni < NF; ++ni)
        acc[MH + mi][ni] = __builtin_amdgcn_mfma_f32_16x16x32_bf16(af[mi], bfr[ni], acc[MH + mi][ni], 0, 0, 0);
    __builtin_amdgcn_s_setprio(0);
    // next-tile loads (issued ph0/ph1) must be complete + visible before
    // next iteration's ds_reads: drain, then barrier.
    asm volatile("s_waitcnt vmcnt(0)" ::: "memory");
    __builtin_amdgcn_s_barrier();
  }

  // ---------- epilogue ----------
  #pragma unroll
  for (int mf = 0; mf < MF; ++mf){
    #pragma unroll
    for (int ni = 0; ni < NF; ++ni){
      #pragma unroll
      for (int r = 0; r < 4; ++r){
        int m = m0 + wm * TM + mf * 16 + rb + r;
        int n = n0 + wn * TN + ni * 16 + lr;
        float v = acc[mf][ni][r];
        if (MODE == 1){
          v = (v + bias[m]) * oscale;
          int b = n >> 11, tt = n & 2047, h = m >> 6, d = m & 63;
          ((unsigned short*)out)[(((size_t)(b * 16 + h) * 64 + d) << 11) + tt] = f2bf(v);
        } else if (MODE == 2){
          v += bias[n];
          ((float*)out)[(size_t)m * N + n] = v;
        } else { // MODE 3: fused Q+K
          int seg = n >> 10, nn = n & 1023;
          v += seg ? bias2[nn] : bias[nn];
          if (!seg) v *= oscale;
          int b = m >> 11, tt = m & 2047, h = nn >> 6, d = nn & 63;
          ((unsigned short*)out)[(size_t)seg * BTOT * DM +
              (((size_t)(b * 16 + h) * 2048 + tt) << 6) + d] = f2bf(v);
        }
      }
    }
  }
}

// ---------- flash attention v11: 8-wave paired blocks, NAMED split PV accumulators ----------
#define ATTN_PV(OD, KB)                                                        \
  {                                                                            \
    unsigned pk0a = cvt_pk_bf16(p[0],  p[1]);                                  \
    unsigned pk0b = cvt_pk_bf16(p[2],  p[3]);                                  \
    unsigned pk1a = cvt_pk_bf16(p[4],  p[5]);                                  \
    unsigned pk1b = cvt_pk_bf16(p[6],  p[7]);                                  \
    unsigned pk2a = cvt_pk_bf16(p[8],  p[9]);                                  \
    unsigned pk2b = cvt_pk_bf16(p[10], p[11]);                                 \
    unsigned pk3a = cvt_pk_bf16(p[12], p[13]);                                 \
    unsigned pk3b = cvt_pk_bf16(p[14], p[15]);                                 \
    __builtin_amdgcn_s_setprio(1);                                             \
    {                                                                          \
      u32x2 r0 = pl32swap(pk0a, pk1a);                                         \
      u32x2 r1 = pl32swap(pk0b, pk1b);                                         \
      union { unsigned u[4]; bf16x8 v; } ap;                                   \
      ap.u[0] = r0[0]; ap.u[1] = r1[0]; ap.u[2] = r0[1]; ap.u[3] = r1[1];      \
      const int wg = (KB) * 2;                                                 \
      _Pragma("unroll")                                                        \
      for (int ntd = 0; ntd < 2; ++ntd){                                       \
        int row = ntd * 32 + l31;                                              \
        bf16x8 bV = *reinterpret_cast<const bf16x8*>(                          \
            &Vs[cur][row * 64 + ((2 * wg + c2) ^ (row & 7)) * 8]);             \
        OD[ntd] = __builtin_amdgcn_mfma_f32_32x32x16_bf16(ap.v, bV, OD[ntd], 0, 0, 0); \
      }                                                                        \
    }                                                                          \
    {                                                                          \
      u32x2 r0 = pl32swap(pk2a, pk3a);                                         \
      u32x2 r1 = pl32swap(pk2b, pk3b);                                         \
      union { unsigned u[4]; bf16x8 v; } ap;                                   \
      ap.u[0] = r0[0]; ap.u[1] = r1[0]; ap.u[2] = r0[1]; ap.u[3] = r1[1];      \
      const int wg = (KB) * 2 + 1;                                             \
      _Pragma("unroll")                                                        \
      for (int ntd = 0; ntd < 2; ++ntd){                                       \
        int row = ntd * 32 + l31;                                              \
        bf16x8 bV = *reinterpret_cast<const bf16x8*>(                          \
            &Vs[cur][row * 64 + ((2 * wg + c2) ^ (row & 7)) * 8]);             \
        OD[ntd] = __builtin_amdgcn_mfma_f32_32x32x16_bf16(ap.v, bV, OD[ntd], 0, 0, 0); \
      }                                                                        \
    }                                                                          \
    __builtin_amdgcn_s_setprio(0);                                             \
  }

#define ATTN_SUBTILE(OD, KB)                                                   \
  {                                                                            \
    const int kvb = kv0 + (KB) * 32;                                           \
    if (kvb <= wave_max){                                                      \
      f32x16 st = {};                                                          \
      __builtin_amdgcn_s_setprio(1);                                           \
      _Pragma("unroll")                                                        \
      for (int m = 0; m < 4; ++m){                                             \
        int row = (KB) * 32 + l31;                                             \
        bf16x8 aK = *reinterpret_cast<const bf16x8*>(                          \
            &Ks[cur][row * 64 + ((2 * m + c2) ^ (row & 7)) * 8]);              \
        st = __builtin_amdgcn_mfma_f32_32x32x16_bf16(aK, bQ[m], st, 0, 0, 0);  \
      }                                                                        \
      __builtin_amdgcn_s_setprio(0);                                           \
      const bool need_mask = (kvb + 31 > q0);                                  \
      float p[16];                                                             \
      _Pragma("unroll")                                                        \
      for (int rg = 0; rg < 16; ++rg){                                         \
        float pv = exp2_raw(st[rg]);                                           \
        if (need_mask){                                                        \
          int kv = kvb + 4 * c2 + 8 * (rg >> 2) + (rg & 3);                    \
          pv = (kv > qrow) ? 0.f : pv;                                         \
        }                                                                      \
        p[rg] = pv;                                                            \
      }                                                                        \
      {                                                                        \
        float s0 = (p[0] + p[1]) + (p[2] + p[3]);                              \
        float s1 = (p[4] + p[5]) + (p[6] + p[7]);                              \
        float s2 = (p[8] + p[9]) + (p[10] + p[11]);                            \
        float s3 = (p[12] + p[13]) + (p[14] + p[15]);                          \
        l_part += (s0 + s1) + (s2 + s3);                                       \
      }                                                                        \
      ATTN_PV(OD, KB)                                                          \
    }                                                                          \
  }

__global__ __launch_bounds__(512) void k_attn(
    const unsigned short* __restrict__ Qb,   // [B*H][T][64] bf16 (pre-scaled)
    const unsigned short* __restrict__ Kb,   // [B*H][T][64] bf16
    const unsigned short* __restrict__ Vt,   // [B*H][64][T] bf16
    unsigned short* __restrict__ Ya)         // [B*T][1024]  bf16
{
  __shared__ unsigned short Ks[2][64 * 64];   // 8 KB x2
  __shared__ unsigned short Vs[2][64 * 64];   // 8 KB x2

  const int t    = threadIdx.x;
  const int lane = t & 63;
  const int w    = t >> 6;                       // wave 0..7
  const int bh   = blockIdx.y;
  const int blk  = blockIdx.x;                   // pair index 0..7
  const int l31  = lane & 31;
  const int c2   = lane >> 5;

  const unsigned short* Qp = Qb + (size_t)bh * TSEQ * 64;
  const unsigned short* Kp = Kb + (size_t)bh * TSEQ * 64;
  const unsigned short* Vp = Vt + (size_t)bh * 64 * TSEQ;
  const int b = bh >> 4, h = bh & 15;

  const int qt   = (w >> 2) ? (15 - blk) : blk;  // this wave-group's q-tile
  const int q0   = qt * 128 + (w & 3) * 32;      // wave's first q-row
  const int wave_max = q0 + 31;
  const int ntiles   = 2 * (15 - blk) + 2;       // covers both q-tiles
  const int qrow = q0 + l31;                     // this lane's q-row

  // stage one 64-row K tile + V tile: 512 threads x (1 K + 1 V) = 2 loads/thread
  auto stage = [&](int buf, int kv0){
    int row = t >> 3, c = t & 7;
    int cs = c ^ (row & 7);
    gload_lds16(Kp + (size_t)(kv0 + row) * 64 + cs * 8, &Ks[buf][t * 8]);
    gload_lds16(Vp + (size_t)row * TSEQ + kv0 + cs * 8, &Vs[buf][t * 8]);
  };

  // Q as B-fragments: 4 k-windows of 16
  bf16x8 bQ[4];
  #pragma unroll
  for (int m = 0; m < 4; ++m)
    bQ[m] = *reinterpret_cast<const bf16x8*>(
        Qp + (size_t)qrow * 64 + m * 16 + c2 * 8);

  f32x16 oA[2] = {}, oB[2] = {};
  float l_part = 0.f;

  stage(0, 0);
  int cur = 0;

  for (int it = 0; it < ntiles; ++it){
    __builtin_amdgcn_sched_barrier(0);
    __builtin_amdgcn_s_barrier();              // barA: all waves done reading buf[cur^1]
    if (it + 1 < ntiles){
      stage(cur ^ 1, (it + 1) * 64);           // prefetch next tile
      asm volatile("s_waitcnt vmcnt(2)" ::: "memory");   // wait only current tile's loads
    } else {
      asm volatile("s_waitcnt vmcnt(0)" ::: "memory");
    }
    __builtin_amdgcn_s_barrier();              // barB: every wave's cur-loads landed
    __builtin_amdgcn_sched_barrier(0);

    const int kv0 = it * 64;
    ATTN_SUBTILE(oA, 0)
    ATTN_SUBTILE(oB, 1)
    cur ^= 1;
  }

  // ---- epilogue: merge split accumulators, reduce l, normalize, store ----
  float l_full = l_part + __shfl_xor(l_part, 32);
  float linv[16];
  #pragma unroll
  for (int rg = 0; rg < 16; ++rg){
    int qloc = 4 * c2 + 8 * (rg >> 2) + (rg & 3);
    linv[rg] = __builtin_amdgcn_rcpf(__shfl(l_full, qloc));
  }
  #pragma unroll
  for (int ntd = 0; ntd < 2; ++ntd)
    #pragma unroll
    for (int rg = 0; rg < 16; ++rg){
      int q = q0 + 4 * c2 + 8 * (rg >> 2) + (rg & 3);
      int d = ntd * 32 + l31;
      float v = (oA[ntd][rg] + oB[ntd][rg]) * linv[rg];
      Ya[((size_t)(b * 2048 + q)) * 1024 + h * 64 + d] = f2bf(v);
    }
}

extern "C" void kernel_launch(void* const* d_in, const int* in_sizes, int n_in,
                              void* d_out, int out_size, void* d_ws, size_t ws_size,
                              hipStream_t stream)
{
  const float* x  = (const float*)d_in[0];
  const float* Wq = (const float*)d_in[1];
  const float* bq = (const float*)d_in[2];
  const float* Wk = (const float*)d_in[3];
  const float* bk = (const float*)d_in[4];
  const float* Wv = (const float*)d_in[5];
  const float* bv = (const float*)d_in[6];
  const float* Wp = (const float*)d_in[7];
  const float* bp = (const float*)d_in[8];
  float* out = (float*)d_out;

  unsigned short* ws   = (unsigned short*)d_ws;
  unsigned short* x_bf = ws;                              // 8192*1024
  unsigned short* Wq_t = x_bf + (size_t)BTOT * DM;        // 1024*1024 each
  unsigned short* Wk_t = Wq_t + (size_t)DM * DM;          // contiguous after Wq_t
  unsigned short* Wv_t = Wk_t + (size_t)DM * DM;
  unsigned short* Wp_t = Wv_t + (size_t)DM * DM;
  unsigned short* Qb   = Wp_t + (size_t)DM * DM;          // 8192*1024
  unsigned short* Kb   = Qb   + (size_t)BTOT * DM;        // contiguous after Qb
  unsigned short* Vt   = Kb   + (size_t)BTOT * DM;
  unsigned short* Ya   = Vt   + (size_t)BTOT * DM;

  // softmax scale folded into Q: 1/sqrt(64) * log2(e)
  const float QSCALE = 0.125f * 1.44269504f;

  // fused prep: cast x (8192 blocks, full coverage) + transpose all 4 weights
  k_prep<<<8192 + 4096, 256, 0, stream>>>(
      x, x_bf, Wq, Wk, Wv, Wp, Wq_t, Wk_t, Wv_t, Wp_t);

  // fused Q+K: (x @ [Wq|Wk]) -> Qb, Kb  (256x256 tile, 256 blocks)
  k_gemm2<3, 256, 256, 2, 4><<<dim3(2048 / 256, BTOT / 256), 512, 0, stream>>>(
      x_bf, Wq_t, bq, bk, Qb, BTOT, 2048, DM, QSCALE);
  // V^T: Wv_t (M=1024) x x_bf (N=8192) -> [B,H,Dh,T]  (128x256 tile, 256 blocks)
  k_gemm2<1, 128, 256, 2, 4><<<dim3(BTOT / 256, DM / 128), 512, 0, stream>>>(
      Wv_t, x_bf, bv, nullptr, Vt, DM, BTOT, DM, 1.0f);

  k_attn<<<dim3(8, NB * NHEAD), 512, 0, stream>>>(Qb, Kb, Vt, Ya);

  // out-proj: Ya (M=8192) x Wp_t (N=1024) -> fp32  (256x128 tile, 256 blocks)
  k_gemm2<2, 256, 128, 4, 2><<<dim3(DM / 128, BTOT / 256), 512, 0, stream>>>(
      Ya, Wp_t, bp, nullptr, out, BTOT, DM, DM, 1.0f);
}

// Round 17
// 161.295 us; speedup vs baseline: 1.3462x; 1.0855x over previous
//
#include <hip/hip_runtime.h>
#include <hip/hip_bf16.h>
#include <stdint.h>

// Problem constants
#define TSEQ 2048
#define NB   4
#define NHEAD 16
#define HDIM 64
#define DM   1024
#define BTOT (NB*TSEQ)   // 8192 tokens

typedef __attribute__((ext_vector_type(8))) short bf16x8;   // 8 bf16 (4 VGPRs)
typedef __attribute__((ext_vector_type(4))) float f32x4;    // 16x16 MFMA C/D
typedef __attribute__((ext_vector_type(16))) float f32x16;  // 32x32 MFMA C/D
typedef __attribute__((ext_vector_type(2))) unsigned u32x2;

__device__ __forceinline__ unsigned short f2bf(float f){
  union { float f; unsigned u; } v; v.f = f;
  unsigned r = v.u + 0x7fffu + ((v.u >> 16) & 1u);   // RNE
  return (unsigned short)(r >> 16);
}

__device__ __forceinline__ unsigned cvt_pk_bf16(float lo, float hi){
  unsigned r;
  asm("v_cvt_pk_bf16_f32 %0, %1, %2" : "=v"(r) : "v"(lo), "v"(hi));
  return r;
}

// raw 2^x via compiler-aware intrinsic (R11-verified win vs exp2f libcall)
__device__ __forceinline__ float exp2_raw(float x){
#if __has_builtin(__builtin_amdgcn_exp2f)
  return __builtin_amdgcn_exp2f(x);
#else
  return exp2f(x);
#endif
}

__device__ __forceinline__ u32x2 pl32swap(unsigned a, unsigned b){
  auto r = __builtin_amdgcn_permlane32_swap((int)a, (int)b, false, false);
  return (u32x2){(unsigned)r[0], (unsigned)r[1]};
}

__device__ __forceinline__ void gload_lds16(const void* g, void* l){
  __builtin_amdgcn_global_load_lds(
      (const __attribute__((address_space(1))) void*)g,
      (__attribute__((address_space(3))) void*)l,
      16, 0, 0);
}

// ---------- fused prep: x cast (blocks 0..8191, FULL coverage) + 4 weight transposes ----------
__global__ __launch_bounds__(256) void k_prep(
    const float* __restrict__ x, unsigned short* __restrict__ x_bf,
    const float* __restrict__ Wq, const float* __restrict__ Wk,
    const float* __restrict__ Wv, const float* __restrict__ Wp,
    unsigned short* __restrict__ Wq_t, unsigned short* __restrict__ Wk_t,
    unsigned short* __restrict__ Wv_t, unsigned short* __restrict__ Wp_t)
{
  __shared__ unsigned short tile_s[32][33];
  const int bid = blockIdx.x;
  if (bid < 8192){
    size_t j = ((size_t)bid * 256 + threadIdx.x) * 4;
    float4 v = *reinterpret_cast<const float4*>(x + j);
    unsigned long long pk =  (unsigned long long)f2bf(v.x)
                          | ((unsigned long long)f2bf(v.y) << 16)
                          | ((unsigned long long)f2bf(v.z) << 32)
                          | ((unsigned long long)f2bf(v.w) << 48);
    *reinterpret_cast<unsigned long long*>(x_bf + j) = pk;
  } else {
    const int r   = bid - 8192;
    const int job = r >> 10, tile = r & 1023;
    const float* W = (job == 0) ? Wq : (job == 1) ? Wk : (job == 2) ? Wv : Wp;
    unsigned short* Wt = (job == 0) ? Wq_t : (job == 1) ? Wk_t : (job == 2) ? Wv_t : Wp_t;
    const int n0 = (tile & 31) * 32, k0 = (tile >> 5) * 32;
    const int tx = threadIdx.x & 31, ty = threadIdx.x >> 5;   // 32 x 8
    #pragma unroll
    for (int j = ty; j < 32; j += 8)
      tile_s[j][tx] = f2bf(W[(size_t)(k0 + j) * DM + n0 + tx]);
    __syncthreads();
    #pragma unroll
    for (int j = ty; j < 32; j += 8)
      Wt[(size_t)(n0 + j) * DM + k0 + tx] = tile_s[tx][j];
  }
}

// ---------- bf16 GEMM body: templated tile, BK=64, 8 waves, 4-phase quadrant schedule ----------
// (device function so independent GEMMs can be fused into one dispatch,
// sharing a caller-provided LDS buffer; schedule identical to R16's k_gemm2)
// MODE 1: out bf16 at [B,H,Dh,T] from (m=h*64+d, n=bt), bias[m]   (V proj)
// MODE 2: out fp32 row-major [M][N], bias[n]                      (final proj)
// MODE 3: fused Q+K: n<1024 -> Q (scaled), else K; out [B,H,T,Dh] x2
template<int MODE, int BM, int BN, int WM, int WN>
__device__ __forceinline__ void gemm_body(
    char* ldsraw,
    const unsigned short* __restrict__ A,    // [M][K] bf16
    const unsigned short* __restrict__ Bt,   // [N][K] bf16
    const float* __restrict__ bias,
    const float* __restrict__ bias2,
    void* __restrict__ out, int M, int N, int K, float oscale,
    int lid, int gx)                          // block id within segment (nwg=256), grid-x of segment
{
  constexpr int TM = BM / WM, TN = BN / WN;   // per-wave output tile
  constexpr int MF = TM / 16, NF = TN / 16;   // fragment counts
  constexpr int MH = MF / 2;                  // m-half fragment count
  constexpr int AH = BM / 2,  BH = BN / 2;    // rows per LDS half
  unsigned short* AsB = (unsigned short*)ldsraw;          // [2][2][AH*64]
  unsigned short* BsB = AsB + 2 * 2 * AH * 64;            // [2][2][BH*64]
  auto As = [&](int buf, int ht){ return AsB + (buf * 2 + ht) * (AH * 64); };
  auto Bs = [&](int buf, int ht){ return BsB + (buf * 2 + ht) * (BH * 64); };

  const int t    = threadIdx.x;
  const int lane = t & 63;
  const int w    = t >> 6;                 // 0..7
  const int wm   = w / WN;
  const int wn   = w % WN;
  const int lr   = lane & 15;
  const int ck   = lane >> 4;              // 0..3
  const int rb   = ck << 2;

  // bijective XCD swizzle (segment nwg == 256, multiple of 8)
  const int swz = (lid & 7) * 32 + (lid >> 3);
  const int n0  = (swz % gx) * BN;
  const int m0  = (swz / gx) * BM;

  // wave's read base within the half-tiles
  const int aHalf = (wm * TM) / AH, aBase = (wm * TM) % AH;
  const int bHalf = (wn * TN) / BH, bBase = (wn * TN) % BH;

  auto stgA = [&](int buf, int kt){
    #pragma unroll
    for (int ht = 0; ht < 2; ++ht)
      #pragma unroll
      for (int rr = 0; rr < AH / 64; ++rr){
        int u = t + rr * 512;
        int row = u >> 3, c = u & 7, cs = c ^ (row & 7);
        gload_lds16(A + (size_t)(m0 + ht * AH + row) * K + kt * 64 + cs * 8,
                    As(buf, ht) + u * 8);
      }
  };
  auto stgB = [&](int buf, int kt){
    #pragma unroll
    for (int ht = 0; ht < 2; ++ht)
      #pragma unroll
      for (int rr = 0; rr < BH / 64; ++rr){
        int u = t + rr * 512;
        int row = u >> 3, c = u & 7, cs = c ^ (row & 7);
        gload_lds16(Bt + (size_t)(n0 + ht * BH + row) * K + kt * 64 + cs * 8,
                    Bs(buf, ht) + u * 8);
      }
  };

  f32x4 acc[MF][NF];
  #pragma unroll
  for (int i = 0; i < MF; ++i)
    #pragma unroll
    for (int j = 0; j < NF; ++j) acc[i][j] = (f32x4){0.f, 0.f, 0.f, 0.f};

  const int NT = K >> 6;

  // prologue: both operands of kt=0, drained + visible before first reads
  stgA(0, 0); stgB(0, 0);
  asm volatile("s_waitcnt vmcnt(0)" ::: "memory");
  __builtin_amdgcn_s_barrier();

  for (int kt = 0; kt < NT; ++kt){
    const int cur = kt & 1;
    const unsigned short* Ah = As(cur, aHalf);
    const unsigned short* Bh = Bs(cur, bHalf);
    bf16x8 af[MH], bfr[NF];

    // ---- phase 0: quadrant (mh=0, kh=0); issue stgA(kt+1) ----
    #pragma unroll
    for (int i = 0; i < MH; ++i)
      af[i]  = *reinterpret_cast<const bf16x8*>(&Ah[(aBase + i * 16 + lr) * 64 + (ck ^ (lr & 7)) * 8]);
    #pragma unroll
    for (int i = 0; i < NF; ++i)
      bfr[i] = *reinterpret_cast<const bf16x8*>(&Bh[(bBase + i * 16 + lr) * 64 + (ck ^ (lr & 7)) * 8]);
    if (kt + 1 < NT) stgA(cur ^ 1, kt + 1);
    __builtin_amdgcn_s_barrier();
    asm volatile("s_waitcnt lgkmcnt(0)" ::: "memory");
    __builtin_amdgcn_sched_barrier(0);
    __builtin_amdgcn_s_setprio(1);
    #pragma unroll
    for (int mi = 0; mi < MH; ++mi)
      #pragma unroll
      for (int ni = 0; ni < NF; ++ni)
        acc[mi][ni] = __builtin_amdgcn_mfma_f32_16x16x32_bf16(af[mi], bfr[ni], acc[mi][ni], 0, 0, 0);
    __builtin_amdgcn_s_setprio(0);
    __builtin_amdgcn_s_barrier();

    // ---- phase 1: quadrant (mh=1, kh=0); issue stgB(kt+1); bfr reused ----
    #pragma unroll
    for (int i = 0; i < MH; ++i)
      af[i]  = *reinterpret_cast<const bf16x8*>(&Ah[(aBase + (MH + i) * 16 + lr) * 64 + (ck ^ (lr & 7)) * 8]);
    if (kt + 1 < NT) stgB(cur ^ 1, kt + 1);
    __builtin_amdgcn_s_barrier();
    asm volatile("s_waitcnt lgkmcnt(0)" ::: "memory");
    __builtin_amdgcn_sched_barrier(0);
    __builtin_amdgcn_s_setprio(1);
    #pragma unroll
    for (int mi = 0; mi < MH; ++mi)
      #pragma unroll
      for (int ni = 0; ni < NF; ++ni)
        acc[MH + mi][ni] = __builtin_amdgcn_mfma_f32_16x16x32_bf16(af[mi], bfr[ni], acc[MH + mi][ni], 0, 0, 0);
    __builtin_amdgcn_s_setprio(0);
    __builtin_amdgcn_s_barrier();

    // ---- phase 2: quadrant (mh=0, kh=1) ----
    #pragma unroll
    for (int i = 0; i < MH; ++i)
      af[i]  = *reinterpret_cast<const bf16x8*>(&Ah[(aBase + i * 16 + lr) * 64 + ((4 + ck) ^ (lr & 7)) * 8]);
    #pragma unroll
    for (int i = 0; i < NF; ++i)
      bfr[i] = *reinterpret_cast<const bf16x8*>(&Bh[(bBase + i * 16 + lr) * 64 + ((4 + ck) ^ (lr & 7)) * 8]);
    __builtin_amdgcn_s_barrier();
    asm volatile("s_waitcnt lgkmcnt(0)" ::: "memory");
    __builtin_amdgcn_sched_barrier(0);
    __builtin_amdgcn_s_setprio(1);
    #pragma unroll
    for (int mi = 0; mi < MH; ++mi)
      #pragma unroll
      for (int ni = 0; ni < NF; ++ni)
        acc[mi][ni] = __builtin_amdgcn_mfma_f32_16x16x32_bf16(af[mi], bfr[ni], acc[mi][ni], 0, 0, 0);
    __builtin_amdgcn_s_setprio(0);
    __builtin_amdgcn_s_barrier();

    // ---- phase 3: quadrant (mh=1, kh=1); end-of-tile drain ----
    #pragma unroll
    for (int i = 0; i < MH; ++i)
      af[i]  = *reinterpret_cast<const bf16x8*>(&Ah[(aBase + (MH + i) * 16 + lr) * 64 + ((4 + ck) ^ (lr & 7)) * 8]);
    __builtin_amdgcn_s_barrier();
    asm volatile("s_waitcnt lgkmcnt(0)" ::: "memory");
    __builtin_amdgcn_sched_barrier(0);
    __builtin_amdgcn_s_setprio(1);
    #pragma unroll
    for (int mi = 0; mi < MH; ++mi)
      #pragma unroll
      for (int ni = 0; ni < NF; ++ni)
        acc[MH + mi][ni] = __builtin_amdgcn_mfma_f32_16x16x32_bf16(af[mi], bfr[ni], acc[MH + mi][ni], 0, 0, 0);
    __builtin_amdgcn_s_setprio(0);
    // next-tile loads (issued ph0/ph1) must be complete + visible before
    // next iteration's ds_reads: drain, then barrier.
    asm volatile("s_waitcnt vmcnt(0)" ::: "memory");
    __builtin_amdgcn_s_barrier();
  }

  // ---------- epilogue ----------
  #pragma unroll
  for (int mf = 0; mf < MF; ++mf){
    #pragma unroll
    for (int ni = 0; ni < NF; ++ni){
      #pragma unroll
      for (int r = 0; r < 4; ++r){
        int m = m0 + wm * TM + mf * 16 + rb + r;
        int n = n0 + wn * TN + ni * 16 + lr;
        float v = acc[mf][ni][r];
        if (MODE == 1){
          v = (v + bias[m]) * oscale;
          int b = n >> 11, tt = n & 2047, h = m >> 6, d = m & 63;
          ((unsigned short*)out)[(((size_t)(b * 16 + h) * 64 + d) << 11) + tt] = f2bf(v);
        } else if (MODE == 2){
          v += bias[n];
          ((float*)out)[(size_t)m * N + n] = v;
        } else { // MODE 3: fused Q+K
          int seg = n >> 10, nn = n & 1023;
          v += seg ? bias2[nn] : bias[nn];
          if (!seg) v *= oscale;
          int b = m >> 11, tt = m & 2047, h = nn >> 6, d = nn & 63;
          ((unsigned short*)out)[(size_t)seg * BTOT * DM +
              (((size_t)(b * 16 + h) * 2048 + tt) << 6) + d] = f2bf(v);
        }
      }
    }
  }
}

// ---------- fused QKV projection: blocks 0..255 -> Q+K gemm, 256..511 -> V gemm ----------
// Both segments are independent (read only x_bf + weights); merging removes the
// full-device drain between the two 1-block/CU dispatches (V blocks backfill
// CUs as QK blocks finish) and one launch boundary.
__global__ __launch_bounds__(512) void k_gemm_qkv(
    const unsigned short* __restrict__ x_bf,
    const unsigned short* __restrict__ Wq_t,   // Wk_t contiguous after
    const unsigned short* __restrict__ Wv_t,
    const float* __restrict__ bq, const float* __restrict__ bk,
    const float* __restrict__ bv,
    unsigned short* __restrict__ Qb,           // Kb contiguous after
    unsigned short* __restrict__ Vt, float qscale)
{
  __shared__ __align__(16) char lds[128 * 1024];
  if (blockIdx.x < 256)
    gemm_body<3, 256, 256, 2, 4>(lds, x_bf, Wq_t, bq, bk, Qb,
                                 BTOT, 2048, DM, qscale, blockIdx.x, 8);
  else
    gemm_body<1, 128, 256, 2, 4>(lds, Wv_t, x_bf, bv, nullptr, Vt,
                                 DM, BTOT, DM, 1.0f, blockIdx.x - 256, 32);
}

// ---------- out-projection ----------
__global__ __launch_bounds__(512) void k_gemm_out(
    const unsigned short* __restrict__ Ya,
    const unsigned short* __restrict__ Wp_t,
    const float* __restrict__ bp, float* __restrict__ out)
{
  __shared__ __align__(16) char lds[96 * 1024];
  int lid = blockIdx.y * gridDim.x + blockIdx.x;
  gemm_body<2, 256, 128, 4, 2>(lds, Ya, Wp_t, bp, nullptr, out,
                               BTOT, DM, DM, 1.0f, lid, 8);
}

// ---------- flash attention v11: 8-wave paired blocks, NAMED split PV accumulators ----------
#define ATTN_PV(OD, KB)                                                        \
  {                                                                            \
    unsigned pk0a = cvt_pk_bf16(p[0],  p[1]);                                  \
    unsigned pk0b = cvt_pk_bf16(p[2],  p[3]);                                  \
    unsigned pk1a = cvt_pk_bf16(p[4],  p[5]);                                  \
    unsigned pk1b = cvt_pk_bf16(p[6],  p[7]);                                  \
    unsigned pk2a = cvt_pk_bf16(p[8],  p[9]);                                  \
    unsigned pk2b = cvt_pk_bf16(p[10], p[11]);                                 \
    unsigned pk3a = cvt_pk_bf16(p[12], p[13]);                                 \
    unsigned pk3b = cvt_pk_bf16(p[14], p[15]);                                 \
    __builtin_amdgcn_s_setprio(1);                                             \
    {                                                                          \
      u32x2 r0 = pl32swap(pk0a, pk1a);                                         \
      u32x2 r1 = pl32swap(pk0b, pk1b);                                         \
      union { unsigned u[4]; bf16x8 v; } ap;                                   \
      ap.u[0] = r0[0]; ap.u[1] = r1[0]; ap.u[2] = r0[1]; ap.u[3] = r1[1];      \
      const int wg = (KB) * 2;                                                 \
      _Pragma("unroll")                                                        \
      for (int ntd = 0; ntd < 2; ++ntd){                                       \
        int row = ntd * 32 + l31;                                              \
        bf16x8 bV = *reinterpret_cast<const bf16x8*>(                          \
            &Vs[cur][row * 64 + ((2 * wg + c2) ^ (row & 7)) * 8]);             \
        OD[ntd] = __builtin_amdgcn_mfma_f32_32x32x16_bf16(ap.v, bV, OD[ntd], 0, 0, 0); \
      }                                                                        \
    }                                                                          \
    {                                                                          \
      u32x2 r0 = pl32swap(pk2a, pk3a);                                         \
      u32x2 r1 = pl32swap(pk2b, pk3b);                                         \
      union { unsigned u[4]; bf16x8 v; } ap;                                   \
      ap.u[0] = r0[0]; ap.u[1] = r1[0]; ap.u[2] = r0[1]; ap.u[3] = r1[1];      \
      const int wg = (KB) * 2 + 1;                                             \
      _Pragma("unroll")                                                        \
      for (int ntd = 0; ntd < 2; ++ntd){                                       \
        int row = ntd * 32 + l31;                                              \
        bf16x8 bV = *reinterpret_cast<const bf16x8*>(                          \
            &Vs[cur][row * 64 + ((2 * wg + c2) ^ (row & 7)) * 8]);             \
        OD[ntd] = __builtin_amdgcn_mfma_f32_32x32x16_bf16(ap.v, bV, OD[ntd], 0, 0, 0); \
      }                                                                        \
    }                                                                          \
    __builtin_amdgcn_s_setprio(0);                                             \
  }

#define ATTN_SUBTILE(OD, KB)                                                   \
  {                                                                            \
    const int kvb = kv0 + (KB) * 32;                                           \
    if (kvb <= wave_max){                                                      \
      f32x16 st = {};                                                          \
      __builtin_amdgcn_s_setprio(1);                                           \
      _Pragma("unroll")                                                        \
      for (int m = 0; m < 4; ++m){                                             \
        int row = (KB) * 32 + l31;                                             \
        bf16x8 aK = *reinterpret_cast<const bf16x8*>(                          \
            &Ks[cur][row * 64 + ((2 * m + c2) ^ (row & 7)) * 8]);              \
        st = __builtin_amdgcn_mfma_f32_32x32x16_bf16(aK, bQ[m], st, 0, 0, 0);  \
      }                                                                        \
      __builtin_amdgcn_s_setprio(0);                                           \
      const bool need_mask = (kvb + 31 > q0);                                  \
      float p[16];                                                             \
      _Pragma("unroll")                                                        \
      for (int rg = 0; rg < 16; ++rg){                                         \
        float pv = exp2_raw(st[rg]);                                           \
        if (need_mask){                                                        \
          int kv = kvb + 4 * c2 + 8 * (rg >> 2) + (rg & 3);                    \
          pv = (kv > qrow) ? 0.f : pv;                                         \
        }                                                                      \
        p[rg] = pv;                                                            \
      }                                                                        \
      {                                                                        \
        float s0 = (p[0] + p[1]) + (p[2] + p[3]);                              \
        float s1 = (p[4] + p[5]) + (p[6] + p[7]);                              \
        float s2 = (p[8] + p[9]) + (p[10] + p[11]);                            \
        float s3 = (p[12] + p[13]) + (p[14] + p[15]);                          \
        l_part += (s0 + s1) + (s2 + s3);                                       \
      }                                                                        \
      ATTN_PV(OD, KB)                                                          \
    }                                                                          \
  }

__global__ __launch_bounds__(512) void k_attn(
    const unsigned short* __restrict__ Qb,   // [B*H][T][64] bf16 (pre-scaled)
    const unsigned short* __restrict__ Kb,   // [B*H][T][64] bf16
    const unsigned short* __restrict__ Vt,   // [B*H][64][T] bf16
    unsigned short* __restrict__ Ya)         // [B*T][1024]  bf16
{
  __shared__ unsigned short Ks[2][64 * 64];   // 8 KB x2
  __shared__ unsigned short Vs[2][64 * 64];   // 8 KB x2

  const int t    = threadIdx.x;
  const int lane = t & 63;
  const int w    = t >> 6;                       // wave 0..7
  const int bh   = blockIdx.y;
  const int blk  = blockIdx.x;                   // pair index 0..7
  const int l31  = lane & 31;
  const int c2   = lane >> 5;

  const unsigned short* Qp = Qb + (size_t)bh * TSEQ * 64;
  const unsigned short* Kp = Kb + (size_t)bh * TSEQ * 64;
  const unsigned short* Vp = Vt + (size_t)bh * 64 * TSEQ;
  const int b = bh >> 4, h = bh & 15;

  const int qt   = (w >> 2) ? (15 - blk) : blk;  // this wave-group's q-tile
  const int q0   = qt * 128 + (w & 3) * 32;      // wave's first q-row
  const int wave_max = q0 + 31;
  const int ntiles   = 2 * (15 - blk) + 2;       // covers both q-tiles
  const int qrow = q0 + l31;                     // this lane's q-row

  // stage one 64-row K tile + V tile: 512 threads x (1 K + 1 V) = 2 loads/thread
  auto stage = [&](int buf, int kv0){
    int row = t >> 3, c = t & 7;
    int cs = c ^ (row & 7);
    gload_lds16(Kp + (size_t)(kv0 + row) * 64 + cs * 8, &Ks[buf][t * 8]);
    gload_lds16(Vp + (size_t)row * TSEQ + kv0 + cs * 8, &Vs[buf][t * 8]);
  };

  // Q as B-fragments: 4 k-windows of 16
  bf16x8 bQ[4];
  #pragma unroll
  for (int m = 0; m < 4; ++m)
    bQ[m] = *reinterpret_cast<const bf16x8*>(
        Qp + (size_t)qrow * 64 + m * 16 + c2 * 8);

  f32x16 oA[2] = {}, oB[2] = {};
  float l_part = 0.f;

  stage(0, 0);
  int cur = 0;

  for (int it = 0; it < ntiles; ++it){
    __builtin_amdgcn_sched_barrier(0);
    __builtin_amdgcn_s_barrier();              // barA: all waves done reading buf[cur^1]
    if (it + 1 < ntiles){
      stage(cur ^ 1, (it + 1) * 64);           // prefetch next tile
      asm volatile("s_waitcnt vmcnt(2)" ::: "memory");   // wait only current tile's loads
    } else {
      asm volatile("s_waitcnt vmcnt(0)" ::: "memory");
    }
    __builtin_amdgcn_s_barrier();              // barB: every wave's cur-loads landed
    __builtin_amdgcn_sched_barrier(0);

    const int kv0 = it * 64;
    ATTN_SUBTILE(oA, 0)
    ATTN_SUBTILE(oB, 1)
    cur ^= 1;
  }

  // ---- epilogue: merge split accumulators, reduce l, normalize, store ----
  float l_full = l_part + __shfl_xor(l_part, 32);
  float linv[16];
  #pragma unroll
  for (int rg = 0; rg < 16; ++rg){
    int qloc = 4 * c2 + 8 * (rg >> 2) + (rg & 3);
    linv[rg] = __builtin_amdgcn_rcpf(__shfl(l_full, qloc));
  }
  #pragma unroll
  for (int ntd = 0; ntd < 2; ++ntd)
    #pragma unroll
    for (int rg = 0; rg < 16; ++rg){
      int q = q0 + 4 * c2 + 8 * (rg >> 2) + (rg & 3);
      int d = ntd * 32 + l31;
      float v = (oA[ntd][rg] + oB[ntd][rg]) * linv[rg];
      Ya[((size_t)(b * 2048 + q)) * 1024 + h * 64 + d] = f2bf(v);
    }
}

extern "C" void kernel_launch(void* const* d_in, const int* in_sizes, int n_in,
                              void* d_out, int out_size, void* d_ws, size_t ws_size,
                              hipStream_t stream)
{
  const float* x  = (const float*)d_in[0];
  const float* Wq = (const float*)d_in[1];
  const float* bq = (const float*)d_in[2];
  const float* Wk = (const float*)d_in[3];
  const float* bk = (const float*)d_in[4];
  const float* Wv = (const float*)d_in[5];
  const float* bv = (const float*)d_in[6];
  const float* Wp = (const float*)d_in[7];
  const float* bp = (const float*)d_in[8];
  float* out = (float*)d_out;

  unsigned short* ws   = (unsigned short*)d_ws;
  unsigned short* x_bf = ws;                              // 8192*1024
  unsigned short* Wq_t = x_bf + (size_t)BTOT * DM;        // 1024*1024 each
  unsigned short* Wk_t = Wq_t + (size_t)DM * DM;          // contiguous after Wq_t
  unsigned short* Wv_t = Wk_t + (size_t)DM * DM;
  unsigned short* Wp_t = Wv_t + (size_t)DM * DM;
  unsigned short* Qb   = Wp_t + (size_t)DM * DM;          // 8192*1024
  unsigned short* Kb   = Qb   + (size_t)BTOT * DM;        // contiguous after Qb
  unsigned short* Vt   = Kb   + (size_t)BTOT * DM;
  unsigned short* Ya   = Vt   + (size_t)BTOT * DM;

  // softmax scale folded into Q: 1/sqrt(64) * log2(e)
  const float QSCALE = 0.125f * 1.44269504f;

  // fused prep: cast x (8192 blocks, full coverage) + transpose all 4 weights
  k_prep<<<8192 + 4096, 256, 0, stream>>>(
      x, x_bf, Wq, Wk, Wv, Wp, Wq_t, Wk_t, Wv_t, Wp_t);

  // fused QKV projections: one 512-block dispatch (QK segment + V segment)
  k_gemm_qkv<<<512, 512, 0, stream>>>(
      x_bf, Wq_t, Wv_t, bq, bk, bv, Qb, Vt, QSCALE);

  k_attn<<<dim3(8, NB * NHEAD), 512, 0, stream>>>(Qb, Kb, Vt, Ya);

  // out-proj: Ya (M=8192) x Wp_t (N=1024) -> fp32  (256x128 tile, 256 blocks)
  k_gemm_out<<<dim3(8, 32), 512, 0, stream>>>(Ya, Wp_t, bp, out);
}

// Round 18
// 153.776 us; speedup vs baseline: 1.4120x; 1.0489x over previous
//
#include <hip/hip_runtime.h>
#include <hip/hip_bf16.h>
#include <stdint.h>

// Problem constants
#define TSEQ 2048
#define NB   4
#define NHEAD 16
#define HDIM 64
#define DM   1024
#define BTOT (NB*TSEQ)   // 8192 tokens

typedef __attribute__((ext_vector_type(8))) short bf16x8;   // 8 bf16 (4 VGPRs)
typedef __attribute__((ext_vector_type(4))) float f32x4;    // 16x16 MFMA C/D
typedef __attribute__((ext_vector_type(16))) float f32x16;  // 32x32 MFMA C/D
typedef __attribute__((ext_vector_type(2))) unsigned u32x2;

__device__ __forceinline__ unsigned short f2bf(float f){
  union { float f; unsigned u; } v; v.f = f;
  unsigned r = v.u + 0x7fffu + ((v.u >> 16) & 1u);   // RNE
  return (unsigned short)(r >> 16);
}

__device__ __forceinline__ unsigned cvt_pk_bf16(float lo, float hi){
  unsigned r;
  asm("v_cvt_pk_bf16_f32 %0, %1, %2" : "=v"(r) : "v"(lo), "v"(hi));
  return r;
}

// raw 2^x via compiler-aware intrinsic (R11-verified win vs exp2f libcall)
__device__ __forceinline__ float exp2_raw(float x){
#if __has_builtin(__builtin_amdgcn_exp2f)
  return __builtin_amdgcn_exp2f(x);
#else
  return exp2f(x);
#endif
}

__device__ __forceinline__ u32x2 pl32swap(unsigned a, unsigned b){
  auto r = __builtin_amdgcn_permlane32_swap((int)a, (int)b, false, false);
  return (u32x2){(unsigned)r[0], (unsigned)r[1]};
}

__device__ __forceinline__ void gload_lds16(const void* g, void* l){
  __builtin_amdgcn_global_load_lds(
      (const __attribute__((address_space(1))) void*)g,
      (__attribute__((address_space(3))) void*)l,
      16, 0, 0);
}

// ---------- fused prep: x cast (blocks 0..8191, FULL coverage) + 4 weight transposes ----------
__global__ __launch_bounds__(256) void k_prep(
    const float* __restrict__ x, unsigned short* __restrict__ x_bf,
    const float* __restrict__ Wq, const float* __restrict__ Wk,
    const float* __restrict__ Wv, const float* __restrict__ Wp,
    unsigned short* __restrict__ Wq_t, unsigned short* __restrict__ Wk_t,
    unsigned short* __restrict__ Wv_t, unsigned short* __restrict__ Wp_t)
{
  __shared__ unsigned short tile_s[32][33];
  const int bid = blockIdx.x;
  if (bid < 8192){
    size_t j = ((size_t)bid * 256 + threadIdx.x) * 4;
    float4 v = *reinterpret_cast<const float4*>(x + j);
    unsigned long long pk =  (unsigned long long)f2bf(v.x)
                          | ((unsigned long long)f2bf(v.y) << 16)
                          | ((unsigned long long)f2bf(v.z) << 32)
                          | ((unsigned long long)f2bf(v.w) << 48);
    *reinterpret_cast<unsigned long long*>(x_bf + j) = pk;
  } else {
    const int r   = bid - 8192;
    const int job = r >> 10, tile = r & 1023;
    const float* W = (job == 0) ? Wq : (job == 1) ? Wk : (job == 2) ? Wv : Wp;
    unsigned short* Wt = (job == 0) ? Wq_t : (job == 1) ? Wk_t : (job == 2) ? Wv_t : Wp_t;
    const int n0 = (tile & 31) * 32, k0 = (tile >> 5) * 32;
    const int tx = threadIdx.x & 31, ty = threadIdx.x >> 5;   // 32 x 8
    #pragma unroll
    for (int j = ty; j < 32; j += 8)
      tile_s[j][tx] = f2bf(W[(size_t)(k0 + j) * DM + n0 + tx]);
    __syncthreads();
    #pragma unroll
    for (int j = ty; j < 32; j += 8)
      Wt[(size_t)(n0 + j) * DM + k0 + tx] = tile_s[tx][j];
  }
}

// ---------- bf16 GEMM body: templated tile, BK=64, 8 waves, 4-phase quadrant schedule ----------
// MODE 1: out bf16 at [B,H,Dh,T] from (m=h*64+d, n=bt), bias[m]   (V proj)
// MODE 2: out fp32 row-major [M][N], bias[n]                      (final proj)
// MODE 3: fused Q+K: n<1024 -> Q (scaled), else K; out [B,H,T,Dh] x2
template<int MODE, int BM, int BN, int WM, int WN>
__device__ __forceinline__ void gemm_body(
    char* ldsraw,
    const unsigned short* __restrict__ A,    // [M][K] bf16
    const unsigned short* __restrict__ Bt,   // [N][K] bf16
    const float* __restrict__ bias,
    const float* __restrict__ bias2,
    void* __restrict__ out, int M, int N, int K, float oscale,
    int lid, int gx)                          // block id within segment (nwg=256), grid-x of segment
{
  constexpr int TM = BM / WM, TN = BN / WN;   // per-wave output tile
  constexpr int MF = TM / 16, NF = TN / 16;   // fragment counts
  constexpr int MH = MF / 2;                  // m-half fragment count
  constexpr int AH = BM / 2,  BH = BN / 2;    // rows per LDS half
  unsigned short* AsB = (unsigned short*)ldsraw;          // [2][2][AH*64]
  unsigned short* BsB = AsB + 2 * 2 * AH * 64;            // [2][2][BH*64]
  auto As = [&](int buf, int ht){ return AsB + (buf * 2 + ht) * (AH * 64); };
  auto Bs = [&](int buf, int ht){ return BsB + (buf * 2 + ht) * (BH * 64); };

  const int t    = threadIdx.x;
  const int lane = t & 63;
  const int w    = t >> 6;                 // 0..7
  const int wm   = w / WN;
  const int wn   = w % WN;
  const int lr   = lane & 15;
  const int ck   = lane >> 4;              // 0..3
  const int rb   = ck << 2;

  // bijective XCD swizzle (segment nwg == 256, multiple of 8)
  const int swz = (lid & 7) * 32 + (lid >> 3);
  const int n0  = (swz % gx) * BN;
  const int m0  = (swz / gx) * BM;

  // wave's read base within the half-tiles
  const int aHalf = (wm * TM) / AH, aBase = (wm * TM) % AH;
  const int bHalf = (wn * TN) / BH, bBase = (wn * TN) % BH;

  auto stgA = [&](int buf, int kt){
    #pragma unroll
    for (int ht = 0; ht < 2; ++ht)
      #pragma unroll
      for (int rr = 0; rr < AH / 64; ++rr){
        int u = t + rr * 512;
        int row = u >> 3, c = u & 7, cs = c ^ (row & 7);
        gload_lds16(A + (size_t)(m0 + ht * AH + row) * K + kt * 64 + cs * 8,
                    As(buf, ht) + u * 8);
      }
  };
  auto stgB = [&](int buf, int kt){
    #pragma unroll
    for (int ht = 0; ht < 2; ++ht)
      #pragma unroll
      for (int rr = 0; rr < BH / 64; ++rr){
        int u = t + rr * 512;
        int row = u >> 3, c = u & 7, cs = c ^ (row & 7);
        gload_lds16(Bt + (size_t)(n0 + ht * BH + row) * K + kt * 64 + cs * 8,
                    Bs(buf, ht) + u * 8);
      }
  };

  f32x4 acc[MF][NF];
  #pragma unroll
  for (int i = 0; i < MF; ++i)
    #pragma unroll
    for (int j = 0; j < NF; ++j) acc[i][j] = (f32x4){0.f, 0.f, 0.f, 0.f};

  const int NT = K >> 6;

  // prologue: both operands of kt=0, drained + visible before first reads
  stgA(0, 0); stgB(0, 0);
  asm volatile("s_waitcnt vmcnt(0)" ::: "memory");
  __builtin_amdgcn_s_barrier();

  for (int kt = 0; kt < NT; ++kt){
    const int cur = kt & 1;
    const unsigned short* Ah = As(cur, aHalf);
    const unsigned short* Bh = Bs(cur, bHalf);
    bf16x8 af[MH], bfr[NF];

    // ---- phase 0: quadrant (mh=0, kh=0); issue stgA(kt+1) ----
    #pragma unroll
    for (int i = 0; i < MH; ++i)
      af[i]  = *reinterpret_cast<const bf16x8*>(&Ah[(aBase + i * 16 + lr) * 64 + (ck ^ (lr & 7)) * 8]);
    #pragma unroll
    for (int i = 0; i < NF; ++i)
      bfr[i] = *reinterpret_cast<const bf16x8*>(&Bh[(bBase + i * 16 + lr) * 64 + (ck ^ (lr & 7)) * 8]);
    if (kt + 1 < NT) stgA(cur ^ 1, kt + 1);
    __builtin_amdgcn_s_barrier();
    asm volatile("s_waitcnt lgkmcnt(0)" ::: "memory");
    __builtin_amdgcn_sched_barrier(0);
    __builtin_amdgcn_s_setprio(1);
    #pragma unroll
    for (int mi = 0; mi < MH; ++mi)
      #pragma unroll
      for (int ni = 0; ni < NF; ++ni)
        acc[mi][ni] = __builtin_amdgcn_mfma_f32_16x16x32_bf16(af[mi], bfr[ni], acc[mi][ni], 0, 0, 0);
    __builtin_amdgcn_s_setprio(0);
    __builtin_amdgcn_s_barrier();

    // ---- phase 1: quadrant (mh=1, kh=0); issue stgB(kt+1); bfr reused ----
    #pragma unroll
    for (int i = 0; i < MH; ++i)
      af[i]  = *reinterpret_cast<const bf16x8*>(&Ah[(aBase + (MH + i) * 16 + lr) * 64 + (ck ^ (lr & 7)) * 8]);
    if (kt + 1 < NT) stgB(cur ^ 1, kt + 1);
    __builtin_amdgcn_s_barrier();
    asm volatile("s_waitcnt lgkmcnt(0)" ::: "memory");
    __builtin_amdgcn_sched_barrier(0);
    __builtin_amdgcn_s_setprio(1);
    #pragma unroll
    for (int mi = 0; mi < MH; ++mi)
      #pragma unroll
      for (int ni = 0; ni < NF; ++ni)
        acc[MH + mi][ni] = __builtin_amdgcn_mfma_f32_16x16x32_bf16(af[mi], bfr[ni], acc[MH + mi][ni], 0, 0, 0);
    __builtin_amdgcn_s_setprio(0);
    __builtin_amdgcn_s_barrier();

    // ---- phase 2: quadrant (mh=0, kh=1) ----
    #pragma unroll
    for (int i = 0; i < MH; ++i)
      af[i]  = *reinterpret_cast<const bf16x8*>(&Ah[(aBase + i * 16 + lr) * 64 + ((4 + ck) ^ (lr & 7)) * 8]);
    #pragma unroll
    for (int i = 0; i < NF; ++i)
      bfr[i] = *reinterpret_cast<const bf16x8*>(&Bh[(bBase + i * 16 + lr) * 64 + ((4 + ck) ^ (lr & 7)) * 8]);
    __builtin_amdgcn_s_barrier();
    asm volatile("s_waitcnt lgkmcnt(0)" ::: "memory");
    __builtin_amdgcn_sched_barrier(0);
    __builtin_amdgcn_s_setprio(1);
    #pragma unroll
    for (int mi = 0; mi < MH; ++mi)
      #pragma unroll
      for (int ni = 0; ni < NF; ++ni)
        acc[mi][ni] = __builtin_amdgcn_mfma_f32_16x16x32_bf16(af[mi], bfr[ni], acc[mi][ni], 0, 0, 0);
    __builtin_amdgcn_s_setprio(0);
    __builtin_amdgcn_s_barrier();

    // ---- phase 3: quadrant (mh=1, kh=1); end-of-tile drain ----
    #pragma unroll
    for (int i = 0; i < MH; ++i)
      af[i]  = *reinterpret_cast<const bf16x8*>(&Ah[(aBase + (MH + i) * 16 + lr) * 64 + ((4 + ck) ^ (lr & 7)) * 8]);
    __builtin_amdgcn_s_barrier();
    asm volatile("s_waitcnt lgkmcnt(0)" ::: "memory");
    __builtin_amdgcn_sched_barrier(0);
    __builtin_amdgcn_s_setprio(1);
    #pragma unroll
    for (int mi = 0; mi < MH; ++mi)
      #pragma unroll
      for (int ni = 0; ni < NF; ++ni)
        acc[MH + mi][ni] = __builtin_amdgcn_mfma_f32_16x16x32_bf16(af[mi], bfr[ni], acc[MH + mi][ni], 0, 0, 0);
    __builtin_amdgcn_s_setprio(0);
    // next-tile loads (issued ph0/ph1) must be complete + visible before
    // next iteration's ds_reads: drain, then barrier.
    asm volatile("s_waitcnt vmcnt(0)" ::: "memory");
    __builtin_amdgcn_s_barrier();
  }

  // ---------- epilogue ----------
  #pragma unroll
  for (int mf = 0; mf < MF; ++mf){
    #pragma unroll
    for (int ni = 0; ni < NF; ++ni){
      #pragma unroll
      for (int r = 0; r < 4; ++r){
        int m = m0 + wm * TM + mf * 16 + rb + r;
        int n = n0 + wn * TN + ni * 16 + lr;
        float v = acc[mf][ni][r];
        if (MODE == 1){
          v = (v + bias[m]) * oscale;
          int b = n >> 11, tt = n & 2047, h = m >> 6, d = m & 63;
          ((unsigned short*)out)[(((size_t)(b * 16 + h) * 64 + d) << 11) + tt] = f2bf(v);
        } else if (MODE == 2){
          v += bias[n];
          ((float*)out)[(size_t)m * N + n] = v;
        } else { // MODE 3: fused Q+K
          int seg = n >> 10, nn = n & 1023;
          v += seg ? bias2[nn] : bias[nn];
          if (!seg) v *= oscale;
          int b = m >> 11, tt = m & 2047, h = nn >> 6, d = nn & 63;
          ((unsigned short*)out)[(size_t)seg * BTOT * DM +
              (((size_t)(b * 16 + h) * 2048 + tt) << 6) + d] = f2bf(v);
        }
      }
    }
  }
}

// ---------- fused QKV projection: blocks 0..255 -> Q+K gemm, 256..511 -> V gemm ----------
__global__ __launch_bounds__(512) void k_gemm_qkv(
    const unsigned short* __restrict__ x_bf,
    const unsigned short* __restrict__ Wq_t,   // Wk_t contiguous after
    const unsigned short* __restrict__ Wv_t,
    const float* __restrict__ bq, const float* __restrict__ bk,
    const float* __restrict__ bv,
    unsigned short* __restrict__ Qb,           // Kb contiguous after
    unsigned short* __restrict__ Vt, float qscale)
{
  __shared__ __align__(16) char lds[128 * 1024];
  if (blockIdx.x < 256)
    gemm_body<3, 256, 256, 2, 4>(lds, x_bf, Wq_t, bq, bk, Qb,
                                 BTOT, 2048, DM, qscale, blockIdx.x, 8);
  else
    gemm_body<1, 128, 256, 2, 4>(lds, Wv_t, x_bf, bv, nullptr, Vt,
                                 DM, BTOT, DM, 1.0f, blockIdx.x - 256, 32);
}

// ---------- out-projection ----------
__global__ __launch_bounds__(512) void k_gemm_out(
    const unsigned short* __restrict__ Ya,
    const unsigned short* __restrict__ Wp_t,
    const float* __restrict__ bp, float* __restrict__ out)
{
  __shared__ __align__(16) char lds[96 * 1024];
  int lid = blockIdx.y * gridDim.x + blockIdx.x;
  gemm_body<2, 256, 128, 4, 2>(lds, Ya, Wp_t, bp, nullptr, out,
                               BTOT, DM, DM, 1.0f, lid, 8);
}

// ---------- flash attention v12: 8-wave paired blocks + XCD-affine bh mapping ----------
// R18 change (T1): 1-D grid of 512 blocks; xcd = L&7, all 8 pair-blocks of a
// bh mapped to the SAME XCD (bh = xcd + 8*(slot&7)) -> per-XCD KV working set
// ~4.2MB ~= L2; K/V fetched ~once per XCD instead of 8 XCDs each.
#define ATTN_PV(OD, KB)                                                        \
  {                                                                            \
    unsigned pk0a = cvt_pk_bf16(p[0],  p[1]);                                  \
    unsigned pk0b = cvt_pk_bf16(p[2],  p[3]);                                  \
    unsigned pk1a = cvt_pk_bf16(p[4],  p[5]);                                  \
    unsigned pk1b = cvt_pk_bf16(p[6],  p[7]);                                  \
    unsigned pk2a = cvt_pk_bf16(p[8],  p[9]);                                  \
    unsigned pk2b = cvt_pk_bf16(p[10], p[11]);                                 \
    unsigned pk3a = cvt_pk_bf16(p[12], p[13]);                                 \
    unsigned pk3b = cvt_pk_bf16(p[14], p[15]);                                 \
    __builtin_amdgcn_s_setprio(1);                                             \
    {                                                                          \
      u32x2 r0 = pl32swap(pk0a, pk1a);                                         \
      u32x2 r1 = pl32swap(pk0b, pk1b);                                         \
      union { unsigned u[4]; bf16x8 v; } ap;                                   \
      ap.u[0] = r0[0]; ap.u[1] = r1[0]; ap.u[2] = r0[1]; ap.u[3] = r1[1];      \
      const int wg = (KB) * 2;                                                 \
      _Pragma("unroll")                                                        \
      for (int ntd = 0; ntd < 2; ++ntd){                                       \
        int row = ntd * 32 + l31;                                              \
        bf16x8 bV = *reinterpret_cast<const bf16x8*>(                          \
            &Vs[cur][row * 64 + ((2 * wg + c2) ^ (row & 7)) * 8]);             \
        OD[ntd] = __builtin_amdgcn_mfma_f32_32x32x16_bf16(ap.v, bV, OD[ntd], 0, 0, 0); \
      }                                                                        \
    }                                                                          \
    {                                                                          \
      u32x2 r0 = pl32swap(pk2a, pk3a);                                         \
      u32x2 r1 = pl32swap(pk2b, pk3b);                                         \
      union { unsigned u[4]; bf16x8 v; } ap;                                   \
      ap.u[0] = r0[0]; ap.u[1] = r1[0]; ap.u[2] = r0[1]; ap.u[3] = r1[1];      \
      const int wg = (KB) * 2 + 1;                                             \
      _Pragma("unroll")                                                        \
      for (int ntd = 0; ntd < 2; ++ntd){                                       \
        int row = ntd * 32 + l31;                                              \
        bf16x8 bV = *reinterpret_cast<const bf16x8*>(                          \
            &Vs[cur][row * 64 + ((2 * wg + c2) ^ (row & 7)) * 8]);             \
        OD[ntd] = __builtin_amdgcn_mfma_f32_32x32x16_bf16(ap.v, bV, OD[ntd], 0, 0, 0); \
      }                                                                        \
    }                                                                          \
    __builtin_amdgcn_s_setprio(0);                                             \
  }

#define ATTN_SUBTILE(OD, KB)                                                   \
  {                                                                            \
    const int kvb = kv0 + (KB) * 32;                                           \
    if (kvb <= wave_max){                                                      \
      f32x16 st = {};                                                          \
      __builtin_amdgcn_s_setprio(1);                                           \
      _Pragma("unroll")                                                        \
      for (int m = 0; m < 4; ++m){                                             \
        int row = (KB) * 32 + l31;                                             \
        bf16x8 aK = *reinterpret_cast<const bf16x8*>(                          \
            &Ks[cur][row * 64 + ((2 * m + c2) ^ (row & 7)) * 8]);              \
        st = __builtin_amdgcn_mfma_f32_32x32x16_bf16(aK, bQ[m], st, 0, 0, 0);  \
      }                                                                        \
      __builtin_amdgcn_s_setprio(0);                                           \
      const bool need_mask = (kvb + 31 > q0);                                  \
      float p[16];                                                             \
      _Pragma("unroll")                                                        \
      for (int rg = 0; rg < 16; ++rg){                                         \
        float pv = exp2_raw(st[rg]);                                           \
        if (need_mask){                                                        \
          int kv = kvb + 4 * c2 + 8 * (rg >> 2) + (rg & 3);                    \
          pv = (kv > qrow) ? 0.f : pv;                                         \
        }                                                                      \
        p[rg] = pv;                                                            \
      }                                                                        \
      {                                                                        \
        float s0 = (p[0] + p[1]) + (p[2] + p[3]);                              \
        float s1 = (p[4] + p[5]) + (p[6] + p[7]);                              \
        float s2 = (p[8] + p[9]) + (p[10] + p[11]);                            \
        float s3 = (p[12] + p[13]) + (p[14] + p[15]);                          \
        l_part += (s0 + s1) + (s2 + s3);                                       \
      }                                                                        \
      ATTN_PV(OD, KB)                                                          \
    }                                                                          \
  }

__global__ __launch_bounds__(512) void k_attn(
    const unsigned short* __restrict__ Qb,   // [B*H][T][64] bf16 (pre-scaled)
    const unsigned short* __restrict__ Kb,   // [B*H][T][64] bf16
    const unsigned short* __restrict__ Vt,   // [B*H][64][T] bf16
    unsigned short* __restrict__ Ya)         // [B*T][1024]  bf16
{
  __shared__ unsigned short Ks[2][64 * 64];   // 8 KB x2
  __shared__ unsigned short Vs[2][64 * 64];   // 8 KB x2

  const int t    = threadIdx.x;
  const int lane = t & 63;
  const int w    = t >> 6;                       // wave 0..7
  // XCD-affine mapping: all 8 pair-blocks of one bh on the same XCD
  const int L    = blockIdx.x;                   // 0..511
  const int xcd  = L & 7, slot = L >> 3;         // slot 0..63
  const int bh   = xcd + 8 * (slot & 7);         // 8 bh per XCD
  const int blk  = slot >> 3;                    // pair index 0..7
  const int l31  = lane & 31;
  const int c2   = lane >> 5;

  const unsigned short* Qp = Qb + (size_t)bh * TSEQ * 64;
  const unsigned short* Kp = Kb + (size_t)bh * TSEQ * 64;
  const unsigned short* Vp = Vt + (size_t)bh * 64 * TSEQ;
  const int b = bh >> 4, h = bh & 15;

  const int qt   = (w >> 2) ? (15 - blk) : blk;  // this wave-group's q-tile
  const int q0   = qt * 128 + (w & 3) * 32;      // wave's first q-row
  const int wave_max = q0 + 31;
  const int ntiles   = 2 * (15 - blk) + 2;       // covers both q-tiles
  const int qrow = q0 + l31;                     // this lane's q-row

  // stage one 64-row K tile + V tile: 512 threads x (1 K + 1 V) = 2 loads/thread
  auto stage = [&](int buf, int kv0){
    int row = t >> 3, c = t & 7;
    int cs = c ^ (row & 7);
    gload_lds16(Kp + (size_t)(kv0 + row) * 64 + cs * 8, &Ks[buf][t * 8]);
    gload_lds16(Vp + (size_t)row * TSEQ + kv0 + cs * 8, &Vs[buf][t * 8]);
  };

  // Q as B-fragments: 4 k-windows of 16
  bf16x8 bQ[4];
  #pragma unroll
  for (int m = 0; m < 4; ++m)
    bQ[m] = *reinterpret_cast<const bf16x8*>(
        Qp + (size_t)qrow * 64 + m * 16 + c2 * 8);

  f32x16 oA[2] = {}, oB[2] = {};
  float l_part = 0.f;

  stage(0, 0);
  int cur = 0;

  for (int it = 0; it < ntiles; ++it){
    __builtin_amdgcn_sched_barrier(0);
    __builtin_amdgcn_s_barrier();              // barA: all waves done reading buf[cur^1]
    if (it + 1 < ntiles){
      stage(cur ^ 1, (it + 1) * 64);           // prefetch next tile
      asm volatile("s_waitcnt vmcnt(2)" ::: "memory");   // wait only current tile's loads
    } else {
      asm volatile("s_waitcnt vmcnt(0)" ::: "memory");
    }
    __builtin_amdgcn_s_barrier();              // barB: every wave's cur-loads landed
    __builtin_amdgcn_sched_barrier(0);

    const int kv0 = it * 64;
    ATTN_SUBTILE(oA, 0)
    ATTN_SUBTILE(oB, 1)
    cur ^= 1;
  }

  // ---- epilogue: merge split accumulators, reduce l, normalize, store ----
  float l_full = l_part + __shfl_xor(l_part, 32);
  float linv[16];
  #pragma unroll
  for (int rg = 0; rg < 16; ++rg){
    int qloc = 4 * c2 + 8 * (rg >> 2) + (rg & 3);
    linv[rg] = __builtin_amdgcn_rcpf(__shfl(l_full, qloc));
  }
  #pragma unroll
  for (int ntd = 0; ntd < 2; ++ntd)
    #pragma unroll
    for (int rg = 0; rg < 16; ++rg){
      int q = q0 + 4 * c2 + 8 * (rg >> 2) + (rg & 3);
      int d = ntd * 32 + l31;
      float v = (oA[ntd][rg] + oB[ntd][rg]) * linv[rg];
      Ya[((size_t)(b * 2048 + q)) * 1024 + h * 64 + d] = f2bf(v);
    }
}

extern "C" void kernel_launch(void* const* d_in, const int* in_sizes, int n_in,
                              void* d_out, int out_size, void* d_ws, size_t ws_size,
                              hipStream_t stream)
{
  const float* x  = (const float*)d_in[0];
  const float* Wq = (const float*)d_in[1];
  const float* bq = (const float*)d_in[2];
  const float* Wk = (const float*)d_in[3];
  const float* bk = (const float*)d_in[4];
  const float* Wv = (const float*)d_in[5];
  const float* bv = (const float*)d_in[6];
  const float* Wp = (const float*)d_in[7];
  const float* bp = (const float*)d_in[8];
  float* out = (float*)d_out;

  unsigned short* ws   = (unsigned short*)d_ws;
  unsigned short* x_bf = ws;                              // 8192*1024
  unsigned short* Wq_t = x_bf + (size_t)BTOT * DM;        // 1024*1024 each
  unsigned short* Wk_t = Wq_t + (size_t)DM * DM;          // contiguous after Wq_t
  unsigned short* Wv_t = Wk_t + (size_t)DM * DM;
  unsigned short* Wp_t = Wv_t + (size_t)DM * DM;
  unsigned short* Qb   = Wp_t + (size_t)DM * DM;          // 8192*1024
  unsigned short* Kb   = Qb   + (size_t)BTOT * DM;        // contiguous after Qb
  unsigned short* Vt   = Kb   + (size_t)BTOT * DM;
  unsigned short* Ya   = Vt   + (size_t)BTOT * DM;

  // softmax scale folded into Q: 1/sqrt(64) * log2(e)
  const float QSCALE = 0.125f * 1.44269504f;

  // fused prep: cast x (8192 blocks, full coverage) + transpose all 4 weights
  k_prep<<<8192 + 4096, 256, 0, stream>>>(
      x, x_bf, Wq, Wk, Wv, Wp, Wq_t, Wk_t, Wv_t, Wp_t);

  // fused QKV projections: one 512-block dispatch (QK segment + V segment)
  k_gemm_qkv<<<512, 512, 0, stream>>>(
      x_bf, Wq_t, Wv_t, bq, bk, bv, Qb, Vt, QSCALE);

  k_attn<<<512, 512, 0, stream>>>(Qb, Kb, Vt, Ya);

  // out-proj: Ya (M=8192) x Wp_t (N=1024) -> fp32  (256x128 tile, 256 blocks)
  k_gemm_out<<<dim3(8, 32), 512, 0, stream>>>(Ya, Wp_t, bp, out);
}